// Round 12
// baseline (4531.507 us; speedup 1.0000x reference)
//
#include <hip/hip_runtime.h>

constexpr int kDepth = 6;
constexpr int kB = 8;
constexpr int kN = 1024;
constexpr int kDim = 768;
constexpr int kH = 12;
constexpr int kDh = 64;
constexpr int kMlp = 3072;
constexpr int kRows = kB * kN;   // 8192
constexpr int kQKV = 2304;       // q(768) k(768) v(768)

typedef __attribute__((ext_vector_type(4))) float f32x4;
typedef __attribute__((ext_vector_type(8))) short bf16x8;

__device__ __forceinline__ f32x4 mfma16x16x32(bf16x8 a, bf16x8 b, f32x4 c) {
  return __builtin_amdgcn_mfma_f32_16x16x32_bf16(a, b, c, 0, 0, 0);
}

__device__ __forceinline__ unsigned short f2bf(float f) {
  unsigned int u = __builtin_bit_cast(unsigned int, f);
  u = u + 0x7FFFu + ((u >> 16) & 1u);
  return (unsigned short)(u >> 16);
}

__device__ __forceinline__ float bf2f(unsigned short u) {
  return __builtin_bit_cast(float, (unsigned int)u << 16);
}

__device__ __forceinline__ void gload_lds16(const void* g, void* l) {
  __builtin_amdgcn_global_load_lds((__attribute__((address_space(1))) void*)g,
                                   (__attribute__((address_space(3))) void*)l,
                                   16, 0, 0);
}

// ---------------- LayerNorm: f32 in -> bf16 out ----------------
__global__ __launch_bounds__(256) void ln_kernel(const float* __restrict__ x,
                                                 const float* __restrict__ gamma,
                                                 const float* __restrict__ beta,
                                                 unsigned short* __restrict__ out) {
  int row = blockIdx.x, tid = threadIdx.x;
  const float* xr = x + (size_t)row * kDim;
  float v0 = xr[tid], v1 = xr[tid + 256], v2 = xr[tid + 512];
  float s = v0 + v1 + v2;
  float q = v0 * v0 + v1 * v1 + v2 * v2;
#pragma unroll
  for (int o = 32; o >= 1; o >>= 1) {
    s += __shfl_xor(s, o);
    q += __shfl_xor(q, o);
  }
  __shared__ float ss[4], sq[4];
  int wid = tid >> 6, lane = tid & 63;
  if (lane == 0) { ss[wid] = s; sq[wid] = q; }
  __syncthreads();
  s = ss[0] + ss[1] + ss[2] + ss[3];
  q = sq[0] + sq[1] + sq[2] + sq[3];
  float mean = s * (1.0f / kDim);
  float var = q * (1.0f / kDim) - mean * mean;
  float rstd = rsqrtf(var + 1e-5f);
  unsigned short* orow = out + (size_t)row * kDim;
  orow[tid]       = f2bf((v0 - mean) * rstd * gamma[tid]       + beta[tid]);
  orow[tid + 256] = f2bf((v1 - mean) * rstd * gamma[tid + 256] + beta[tid + 256]);
  orow[tid + 512] = f2bf((v2 - mean) * rstd * gamma[tid + 512] + beta[tid + 512]);
}

// ---------------- Batched weight transpose: all 5 matrices x all 6 layers ----------------
__global__ __launch_bounds__(256) void transpose_all6(const float* __restrict__ Wq,
                                                      const float* __restrict__ Wkv,
                                                      const float* __restrict__ Wo,
                                                      const float* __restrict__ W1,
                                                      const float* __restrict__ W2,
                                                      unsigned short* __restrict__ wqkvT,
                                                      unsigned short* __restrict__ woT,
                                                      unsigned short* __restrict__ w1T,
                                                      unsigned short* __restrict__ w2T) {
  int t = blockIdx.x;
  int L = t / 6912;
  t -= L * 6912;
  const float* src;
  unsigned short* dst;
  int R, C, dstOff;
  if (t < 576)       { src = Wq  + (size_t)L * 768 * 768;  R = 768;  C = 768;  dst = wqkvT + (size_t)L * kQKV * kDim; dstOff = 0;   }
  else if (t < 1728) { src = Wkv + (size_t)L * 768 * 1536; R = 768;  C = 1536; dst = wqkvT + (size_t)L * kQKV * kDim; dstOff = 768; t -= 576; }
  else if (t < 2304) { src = Wo  + (size_t)L * 768 * 768;  R = 768;  C = 768;  dst = woT  + (size_t)L * kDim * kDim;  dstOff = 0;   t -= 1728; }
  else if (t < 4608) { src = W1  + (size_t)L * 768 * 3072; R = 768;  C = 3072; dst = w1T  + (size_t)L * kMlp * kDim;  dstOff = 0;   t -= 2304; }
  else               { src = W2  + (size_t)L * 3072 * 768; R = 3072; C = 768;  dst = w2T  + (size_t)L * kDim * kMlp;  dstOff = 0;   t -= 4608; }
  int Ct = C >> 5;
  int bx = t % Ct, by = t / Ct;
  __shared__ float tt[32][33];
  int tx = threadIdx.x & 31, ty = threadIdx.x >> 5;  // ty 0..7
  int c0 = bx * 32, r0 = by * 32;
#pragma unroll
  for (int k = 0; k < 4; ++k) {
    int r = r0 + ty + k * 8;
    tt[ty + k * 8][tx] = src[(size_t)r * C + c0 + tx];
  }
  __syncthreads();
#pragma unroll
  for (int k = 0; k < 4; ++k) {
    int c = c0 + ty + k * 8;
    dst[(size_t)(dstOff + c) * R + r0 + tx] = f2bf(tt[tx][ty + k * 8]);
  }
}

// ---------------- V transpose: qkv[b,j,1536+g*64+d] -> vT[(b*12+g)*64+d][j] ----------------
__global__ __launch_bounds__(256) void transpose_v_kernel(const unsigned short* __restrict__ qkv,
                                                          unsigned short* __restrict__ vT) {
  __shared__ unsigned short t[32][33];
  int tx = threadIdx.x & 31, ty = threadIdx.x >> 5;
  int j0 = blockIdx.x * 32, d0 = blockIdx.y * 32;
  int bg = blockIdx.z;
  int b = bg / kH, g = bg % kH;
#pragma unroll
  for (int k = 0; k < 4; ++k) {
    int j = j0 + ty + k * 8;
    t[ty + k * 8][tx] = qkv[(size_t)(b * kN + j) * kQKV + 1536 + g * 64 + d0 + tx];
  }
  __syncthreads();
#pragma unroll
  for (int k = 0; k < 4; ++k) {
    int d = d0 + ty + k * 8;
    vT[((size_t)(b * kH + g) * kDh + d) * kN + j0 + tx] = t[tx][ty + k * 8];
  }
}

// ---------------- GEMM 128x128: A[M,K]bf16 x Bt[N,K]bf16 -> epilogue ----------------
// EPI 0: C=bf16 plain; EPI 1: bf16 gelu(acc+bias); EPI 2: resid += (acc+bias)*scl
template <int EPI>
__global__ __launch_bounds__(256) void gemm_kernel(const unsigned short* __restrict__ A,
                                                   const unsigned short* __restrict__ Bt,
                                                   const float* __restrict__ bias,
                                                   const float* __restrict__ scl,
                                                   float* __restrict__ resid,
                                                   unsigned short* __restrict__ C,
                                                   int K, int ldc) {
  __shared__ __align__(16) unsigned short lA[128 * 64];
  __shared__ __align__(16) unsigned short lB[128 * 64];
  int tid = threadIdx.x, wid = tid >> 6, lane = tid & 63;
  // XCD-aware bijective chunked swizzle (all grids have nwg % 8 == 0)
  int gx = gridDim.x;
  int nwg = gx * gridDim.y;
  int orig = blockIdx.y * gx + blockIdx.x;
  int chunk = nwg >> 3;
  int wg = (orig & 7) * chunk + (orig >> 3);
  int bx = wg % gx, by = wg / gx;
  int row0 = by * 128, col0 = bx * 128;
  int wr = wid >> 1, wc = wid & 1;
  f32x4 zero = {0.f, 0.f, 0.f, 0.f};
  f32x4 acc[4][4];
#pragma unroll
  for (int m = 0; m < 4; ++m)
#pragma unroll
    for (int n = 0; n < 4; ++n) acc[m][n] = zero;

  for (int kt = 0; kt < K; kt += 64) {
    __syncthreads();
#pragma unroll
    for (int t = 0; t < 4; ++t) {
      int cbase = wid * 256 + t * 64;
      int c = cbase + lane;
      int r = c >> 3, slot = c & 7;
      int k8 = slot ^ (r & 7);  // source-swizzle so LDS holds XOR-swizzled layout
      gload_lds16(&A[(size_t)(row0 + r) * K + kt + k8 * 8], &lA[cbase * 8]);
      gload_lds16(&Bt[(size_t)(col0 + r) * K + kt + k8 * 8], &lB[cbase * 8]);
    }
    __syncthreads();
#pragma unroll
    for (int kk = 0; kk < 2; ++kk) {
      bf16x8 af[4], bfr[4];
      int kslot = kk * 4 + (lane >> 4);
#pragma unroll
      for (int m = 0; m < 4; ++m) {
        int r = wr * 64 + m * 16 + (lane & 15);
        af[m] = *reinterpret_cast<const bf16x8*>(&lA[r * 64 + ((kslot ^ (r & 7)) << 3)]);
      }
#pragma unroll
      for (int n = 0; n < 4; ++n) {
        int r = wc * 64 + n * 16 + (lane & 15);
        bfr[n] = *reinterpret_cast<const bf16x8*>(&lB[r * 64 + ((kslot ^ (r & 7)) << 3)]);
      }
#pragma unroll
      for (int m = 0; m < 4; ++m)
#pragma unroll
        for (int n = 0; n < 4; ++n) acc[m][n] = mfma16x16x32(af[m], bfr[n], acc[m][n]);
    }
  }
#pragma unroll
  for (int m = 0; m < 4; ++m)
#pragma unroll
    for (int n = 0; n < 4; ++n)
#pragma unroll
      for (int r4 = 0; r4 < 4; ++r4) {
        int row = row0 + wr * 64 + m * 16 + ((lane >> 4) << 2) + r4;
        int col = col0 + wc * 64 + n * 16 + (lane & 15);
        float v = acc[m][n][r4];
        if (EPI == 0) {
          C[(size_t)row * ldc + col] = f2bf(v);
        } else if (EPI == 1) {
          v += bias[col];
          v = 0.5f * v * (1.f + erff(v * 0.70710678118654752f));
          C[(size_t)row * ldc + col] = f2bf(v);
        } else {
          v = (v + bias[col]) * scl[col];
          size_t idx = (size_t)row * kDim + col;
          resid[idx] = resid[idx] + v;
        }
      }
}

// ---------------- QK^T raw per-head scores -> dots bf16, layout [b][i][j][h16] ----------------
__global__ __launch_bounds__(256) void dots_kernel(const unsigned short* __restrict__ qkv,
                                                   unsigned short* __restrict__ dots,
                                                   int i0, int IC) {
  constexpr int TROW = 24;
  __shared__ __align__(16) unsigned short T[32 * 32 * TROW];  // 48KB
  int tid = threadIdx.x, wid = tid >> 6, lane = tid & 63;
  int kg = lane >> 4, l15 = lane & 15;
  int j0 = blockIdx.x * 32;
  int il0 = blockIdx.y * 32;
  int b = blockIdx.z;
  for (int idx = tid; idx < 2048; idx += 256) {
    int pos = idx >> 1;
    *(unsigned int*)&T[pos * TROW + 12 + (idx & 1) * 2] = 0u;
  }
  f32x4 zero = {0.f, 0.f, 0.f, 0.f};
#pragma unroll
  for (int rep = 0; rep < 3; ++rep) {
    int h = rep * 4 + wid;
    f32x4 acc[2][2];
    acc[0][0] = zero; acc[0][1] = zero; acc[1][0] = zero; acc[1][1] = zero;
#pragma unroll
    for (int kk = 0; kk < 2; ++kk) {
      bf16x8 aq[2], bk[2];
#pragma unroll
      for (int m = 0; m < 2; ++m) {
        int tok = i0 + il0 + m * 16 + l15;
        aq[m] = *reinterpret_cast<const bf16x8*>(
            &qkv[(size_t)(b * kN + tok) * kQKV + h * 64 + kk * 32 + kg * 8]);
      }
#pragma unroll
      for (int n = 0; n < 2; ++n) {
        int tj = j0 + n * 16 + l15;
        bk[n] = *reinterpret_cast<const bf16x8*>(
            &qkv[(size_t)(b * kN + tj) * kQKV + 768 + h * 64 + kk * 32 + kg * 8]);
      }
#pragma unroll
      for (int m = 0; m < 2; ++m)
#pragma unroll
        for (int n = 0; n < 2; ++n) acc[m][n] = mfma16x16x32(aq[m], bk[n], acc[m][n]);
    }
#pragma unroll
    for (int m = 0; m < 2; ++m)
#pragma unroll
      for (int n = 0; n < 2; ++n)
#pragma unroll
        for (int r = 0; r < 4; ++r)
          T[((m * 16 + kg * 4 + r) * 32 + n * 16 + l15) * TROW + h] = f2bf(acc[m][n][r]);
  }
  __syncthreads();
#pragma unroll
  for (int k = 0; k < 8; ++k) {
    int c = tid + k * 256;
    int pos = c >> 1, half = c & 1;
    int ii = pos >> 5, jj = pos & 31;
    *(f32x4*)&dots[((size_t)(b * IC + il0 + ii) * kN + j0 + jj) * 16 + half * 8] =
        *(const f32x4*)&T[pos * TROW + half * 8];
  }
}

// ---------------- MFMA premix + softmax (no-max+clamp) + MFMA postmix -> p bf16 ----------------
__global__ __launch_bounds__(256) void softmax_mix_kernel(const unsigned short* __restrict__ dots,
                                                          const float* __restrict__ pre,
                                                          const float* __restrict__ post,
                                                          unsigned short* __restrict__ pbuf,
                                                          int IC) {
  constexpr int EROW = 24;
  __shared__ __align__(16) unsigned short E[1024 * EROW];   // 48KB
  __shared__ __align__(16) unsigned short preA[16 * 32];
  __shared__ __align__(16) unsigned short postA[16 * 32];
  __shared__ float red[4][16];
  __shared__ float lgs[16];
  int tid = threadIdx.x, wid = tid >> 6, lane = tid & 63;
  int kg = lane >> 4, l15 = lane & 15;
  int i = blockIdx.x, b = blockIdx.y;
  for (int idx = tid; idx < 512; idx += 256) {
    int m = idx >> 5, k = idx & 31;
    preA[idx] = f2bf((m < 12 && k < 12) ? pre[k * 12 + m] * 0.125f : 0.f);
  }
  __syncthreads();
  bf16x8 preF = *(const bf16x8*)&preA[l15 * 32 + kg * 8];
  const unsigned short* drow = dots + (size_t)(b * IC + i) * kN * 16;
  f32x4 zero = {0.f, 0.f, 0.f, 0.f};
  bf16x8 zfrag = {0, 0, 0, 0, 0, 0, 0, 0};
  float psum[4] = {0.f, 0.f, 0.f, 0.f};
#pragma unroll
  for (int grp = 0; grp < 16; ++grp) {
    int j = wid * 256 + grp * 16 + l15;
    bf16x8 bfrag = (kg < 2) ? *(const bf16x8*)&drow[(size_t)j * 16 + kg * 8] : zfrag;
    f32x4 d = mfma16x16x32(preF, bfrag, zero);
    float ee[4];
#pragma unroll
    for (int r = 0; r < 4; ++r) {
      float dc = fminf(fmaxf(d[r], -15.f), 15.f);
      ee[r] = (kg == 3) ? 0.f : __expf(dc);
      psum[r] += ee[r];
    }
    unsigned int w0, w1;
    asm("v_cvt_pk_bf16_f32 %0, %1, %2" : "=v"(w0) : "v"(ee[0]), "v"(ee[1]));
    asm("v_cvt_pk_bf16_f32 %0, %1, %2" : "=v"(w1) : "v"(ee[2]), "v"(ee[3]));
    *(unsigned int*)&E[j * EROW + kg * 4] = w0;
    *(unsigned int*)&E[j * EROW + kg * 4 + 2] = w1;
  }
#pragma unroll
  for (int r = 0; r < 4; ++r) {
    psum[r] += __shfl_xor(psum[r], 1);
    psum[r] += __shfl_xor(psum[r], 2);
    psum[r] += __shfl_xor(psum[r], 4);
    psum[r] += __shfl_xor(psum[r], 8);
  }
  if (l15 == 0) {
#pragma unroll
    for (int r = 0; r < 4; ++r) red[wid][kg * 4 + r] = psum[r];
  }
  __syncthreads();
  if (tid < 16) {
    float s = red[0][tid] + red[1][tid] + red[2][tid] + red[3][tid];
    lgs[tid] = (tid < 12) ? 1.f / s : 0.f;
  }
  __syncthreads();
  for (int idx = tid; idx < 512; idx += 256) {
    int m = idx >> 5, k = idx & 31;
    postA[idx] = f2bf((m < 12 && k < 12) ? post[k * 12 + m] * lgs[k] : 0.f);
  }
  __syncthreads();
  bf16x8 postF = *(const bf16x8*)&postA[l15 * 32 + kg * 8];
#pragma unroll
  for (int grp = 0; grp < 16; ++grp) {
    int j = wid * 256 + grp * 16 + l15;
    bf16x8 efrag = (kg < 2) ? *(const bf16x8*)&E[j * EROW + kg * 8] : zfrag;
    f32x4 d2 = mfma16x16x32(postF, efrag, zero);
    if (kg < 3) {
#pragma unroll
      for (int r = 0; r < 4; ++r) {
        int g2 = kg * 4 + r;
        pbuf[((size_t)(b * kH + g2) * IC + i) * kN + j] = f2bf(d2[r]);
      }
    }
  }
}

// ---------------- PV: out[b,i,g*64+d] = sum_j p[b,g,i,j] * v[b,g,j,d] (32 i-rows/block) --------
__global__ __launch_bounds__(256) void pv_kernel(const unsigned short* __restrict__ pbuf,
                                                 const unsigned short* __restrict__ vT,
                                                 unsigned short* __restrict__ attn_out,
                                                 int i0, int IC) {
  int tid = threadIdx.x, wid = tid >> 6, lane = tid & 63;
  int kg = lane >> 4, l15 = lane & 15;
  int i32 = blockIdx.x * 32;
  int g = blockIdx.y, b = blockIdx.z;
  const unsigned short* prow = pbuf + (size_t)(b * kH + g) * IC * kN;
  const unsigned short* vrow = vT + (size_t)(b * kH + g) * kDh * kN;
  f32x4 zero = {0.f, 0.f, 0.f, 0.f};
  f32x4 acc[2][4];
#pragma unroll
  for (int half = 0; half < 2; ++half)
#pragma unroll
    for (int n = 0; n < 4; ++n) acc[half][n] = zero;
#pragma unroll
  for (int s = 0; s < 8; ++s) {
    int kt = (wid * 8 + s) * 32 + kg * 8;
    bf16x8 ap[2];
#pragma unroll
    for (int half = 0; half < 2; ++half)
      ap[half] = *reinterpret_cast<const bf16x8*>(&prow[(size_t)(i32 + half * 16 + l15) * kN + kt]);
#pragma unroll
    for (int n = 0; n < 4; ++n) {
      bf16x8 bv = *reinterpret_cast<const bf16x8*>(&vrow[(size_t)(n * 16 + l15) * kN + kt]);
#pragma unroll
      for (int half = 0; half < 2; ++half)
        acc[half][n] = mfma16x16x32(ap[half], bv, acc[half][n]);
    }
  }
  __shared__ float red[3][32][64];
  if (wid > 0) {
#pragma unroll
    for (int half = 0; half < 2; ++half)
#pragma unroll
      for (int n = 0; n < 4; ++n)
#pragma unroll
        for (int r = 0; r < 4; ++r)
          red[wid - 1][half * 16 + kg * 4 + r][n * 16 + l15] = acc[half][n][r];
  }
  __syncthreads();
  if (wid == 0) {
#pragma unroll
    for (int half = 0; half < 2; ++half)
#pragma unroll
      for (int n = 0; n < 4; ++n)
#pragma unroll
        for (int r = 0; r < 4; ++r) {
          int rr = half * 16 + kg * 4 + r, cc = n * 16 + l15;
          float v = acc[half][n][r] + red[0][rr][cc] + red[1][rr][cc] + red[2][rr][cc];
          int tok = i0 + i32 + rr;
          attn_out[(size_t)(b * kN + tok) * kDim + g * kDh + cc] = f2bf(v);
        }
  }
}

extern "C" void kernel_launch(void* const* d_in, const int* in_sizes, int n_in,
                              void* d_out, int out_size, void* d_ws, size_t ws_size,
                              hipStream_t stream) {
  (void)in_sizes; (void)n_in; (void)out_size;
  const float* x     = (const float*)d_in[0];
  const float* ln1_g = (const float*)d_in[1];
  const float* ln1_b = (const float*)d_in[2];
  const float* Wq    = (const float*)d_in[3];
  const float* Wkv   = (const float*)d_in[4];
  const float* pre   = (const float*)d_in[5];
  const float* post  = (const float*)d_in[6];
  const float* Wo    = (const float*)d_in[7];
  const float* bo    = (const float*)d_in[8];
  const float* s1    = (const float*)d_in[9];
  const float* ln2_g = (const float*)d_in[10];
  const float* ln2_b = (const float*)d_in[11];
  const float* W1    = (const float*)d_in[12];
  const float* b1    = (const float*)d_in[13];
  const float* W2    = (const float*)d_in[14];
  const float* b2    = (const float*)d_in[15];
  const float* s2    = (const float*)d_in[16];
  float* xo = (float*)d_out;

  char* ws = (char*)d_ws;
  size_t off = 0;
  auto alloc = [&](size_t bytes) -> void* {
    void* p = ws + off;
    off += (bytes + 255) & ~(size_t)255;
    return p;
  };
  unsigned short* h_buf   = (unsigned short*)alloc((size_t)kRows * kDim * 2);
  unsigned short* qkv     = (unsigned short*)alloc((size_t)kRows * kQKV * 2);
  unsigned short* vT      = (unsigned short*)alloc((size_t)kB * kH * kDh * kN * 2);
  unsigned short* attnout = (unsigned short*)alloc((size_t)kRows * kDim * 2);
  unsigned short* mid     = (unsigned short*)alloc((size_t)kRows * kMlp * 2);
  unsigned short* wqkvT   = (unsigned short*)alloc((size_t)kDepth * kQKV * kDim * 2);
  unsigned short* woT     = (unsigned short*)alloc((size_t)kDepth * kDim * kDim * 2);
  unsigned short* w1T     = (unsigned short*)alloc((size_t)kDepth * kMlp * kDim * 2);
  unsigned short* w2T     = (unsigned short*)alloc((size_t)kDepth * kDim * kMlp * 2);

  size_t base = off;
  // per-i-row bytes: dots [b][i][j][16] bf16 = 262144; pbuf [b][g2][i][j] = 196608
  int IC = 1024;
  while (IC > 32 && base + (size_t)IC * (262144 + 196608) + 1024 > ws_size) IC >>= 1;
  unsigned short* dots = (unsigned short*)alloc((size_t)kB * IC * kN * 16 * 2);
  unsigned short* pbuf = (unsigned short*)alloc((size_t)kB * kH * IC * kN * 2);

  hipMemcpyAsync(xo, x, (size_t)kRows * kDim * 4, hipMemcpyDeviceToDevice, stream);
  transpose_all6<<<6 * 6912, 256, 0, stream>>>(Wq, Wkv, Wo, W1, W2, wqkvT, woT, w1T, w2T);

  for (int L = 0; L < kDepth; ++L) {
    const unsigned short* wqkvL = wqkvT + (size_t)L * kQKV * kDim;
    const unsigned short* woL   = woT   + (size_t)L * kDim * kDim;
    const unsigned short* w1L   = w1T   + (size_t)L * kMlp * kDim;
    const unsigned short* w2L   = w2T   + (size_t)L * kDim * kMlp;

    // --- attention block ---
    ln_kernel<<<kRows, 256, 0, stream>>>(xo, ln1_g + L * kDim, ln1_b + L * kDim, h_buf);
    gemm_kernel<0><<<dim3(kQKV / 128, kRows / 128), 256, 0, stream>>>(
        h_buf, wqkvL, nullptr, nullptr, nullptr, qkv, kDim, kQKV);
    transpose_v_kernel<<<dim3(kN / 32, kDh / 32, kB * kH), 256, 0, stream>>>(qkv, vT);

    for (int i0 = 0; i0 < kN; i0 += IC) {
      dots_kernel<<<dim3(kN / 32, IC / 32, kB), 256, 0, stream>>>(qkv, dots, i0, IC);
      softmax_mix_kernel<<<dim3(IC, kB), 256, 0, stream>>>(
          dots, pre + L * 144, post + L * 144, pbuf, IC);
      pv_kernel<<<dim3(IC / 32, kH, kB), 256, 0, stream>>>(pbuf, vT, attnout, i0, IC);
    }
    gemm_kernel<2><<<dim3(kDim / 128, kRows / 128), 256, 0, stream>>>(
        attnout, woL, bo + L * kDim, s1 + L * kDim, xo, nullptr, kDim, kDim);

    // --- MLP block ---
    ln_kernel<<<kRows, 256, 0, stream>>>(xo, ln2_g + L * kDim, ln2_b + L * kDim, h_buf);
    gemm_kernel<1><<<dim3(kMlp / 128, kRows / 128), 256, 0, stream>>>(
        h_buf, w1L, b1 + L * kMlp, nullptr, nullptr, mid, kDim, kMlp);
    gemm_kernel<2><<<dim3(kDim / 128, kRows / 128), 256, 0, stream>>>(
        mid, w2L, b2 + L * kDim, s2 + L * kDim, xo, nullptr, kMlp, kDim);
  }
}

// Round 13
// 3533.438 us; speedup vs baseline: 1.2825x; 1.2825x over previous
//
#include <hip/hip_runtime.h>

constexpr int kDepth = 6;
constexpr int kB = 8;
constexpr int kN = 1024;
constexpr int kDim = 768;
constexpr int kH = 12;
constexpr int kDh = 64;
constexpr int kMlp = 3072;
constexpr int kRows = kB * kN;   // 8192
constexpr int kQKV = 2304;       // q(768) k(768) v(768)

typedef __attribute__((ext_vector_type(4))) float f32x4;
typedef __attribute__((ext_vector_type(8))) short bf16x8;

__device__ __forceinline__ f32x4 mfma16x16x32(bf16x8 a, bf16x8 b, f32x4 c) {
  return __builtin_amdgcn_mfma_f32_16x16x32_bf16(a, b, c, 0, 0, 0);
}

__device__ __forceinline__ unsigned short f2bf(float f) {
  unsigned int u = __builtin_bit_cast(unsigned int, f);
  u = u + 0x7FFFu + ((u >> 16) & 1u);
  return (unsigned short)(u >> 16);
}

__device__ __forceinline__ float bf2f(unsigned short u) {
  return __builtin_bit_cast(float, (unsigned int)u << 16);
}

__device__ __forceinline__ void gload_lds16(const void* g, void* l) {
  __builtin_amdgcn_global_load_lds((__attribute__((address_space(1))) void*)g,
                                   (__attribute__((address_space(3))) void*)l,
                                   16, 0, 0);
}

// ---------------- LayerNorm: f32 in -> bf16 out ----------------
__global__ __launch_bounds__(256) void ln_kernel(const float* __restrict__ x,
                                                 const float* __restrict__ gamma,
                                                 const float* __restrict__ beta,
                                                 unsigned short* __restrict__ out) {
  int row = blockIdx.x, tid = threadIdx.x;
  const float* xr = x + (size_t)row * kDim;
  float v0 = xr[tid], v1 = xr[tid + 256], v2 = xr[tid + 512];
  float s = v0 + v1 + v2;
  float q = v0 * v0 + v1 * v1 + v2 * v2;
#pragma unroll
  for (int o = 32; o >= 1; o >>= 1) {
    s += __shfl_xor(s, o);
    q += __shfl_xor(q, o);
  }
  __shared__ float ss[4], sq[4];
  int wid = tid >> 6, lane = tid & 63;
  if (lane == 0) { ss[wid] = s; sq[wid] = q; }
  __syncthreads();
  s = ss[0] + ss[1] + ss[2] + ss[3];
  q = sq[0] + sq[1] + sq[2] + sq[3];
  float mean = s * (1.0f / kDim);
  float var = q * (1.0f / kDim) - mean * mean;
  float rstd = rsqrtf(var + 1e-5f);
  unsigned short* orow = out + (size_t)row * kDim;
  orow[tid]       = f2bf((v0 - mean) * rstd * gamma[tid]       + beta[tid]);
  orow[tid + 256] = f2bf((v1 - mean) * rstd * gamma[tid + 256] + beta[tid + 256]);
  orow[tid + 512] = f2bf((v2 - mean) * rstd * gamma[tid + 512] + beta[tid + 512]);
}

// ---------------- Batched weight transpose: all 5 matrices of one layer ----------------
__global__ __launch_bounds__(256) void transpose_all(const float* __restrict__ Wq,
                                                     const float* __restrict__ Wkv,
                                                     const float* __restrict__ Wo,
                                                     const float* __restrict__ W1,
                                                     const float* __restrict__ W2,
                                                     unsigned short* __restrict__ wqkvT,
                                                     unsigned short* __restrict__ woT,
                                                     unsigned short* __restrict__ w1T,
                                                     unsigned short* __restrict__ w2T,
                                                     int L) {
  int t = blockIdx.x;
  const float* src;
  unsigned short* dst;
  int R, C, dstOff;
  if (t < 576)       { src = Wq  + (size_t)L * 768 * 768;  R = 768;  C = 768;  dst = wqkvT; dstOff = 0;   }
  else if (t < 1728) { src = Wkv + (size_t)L * 768 * 1536; R = 768;  C = 1536; dst = wqkvT; dstOff = 768; t -= 576; }
  else if (t < 2304) { src = Wo  + (size_t)L * 768 * 768;  R = 768;  C = 768;  dst = woT;   dstOff = 0;   t -= 1728; }
  else if (t < 4608) { src = W1  + (size_t)L * 768 * 3072; R = 768;  C = 3072; dst = w1T;   dstOff = 0;   t -= 2304; }
  else               { src = W2  + (size_t)L * 3072 * 768; R = 3072; C = 768;  dst = w2T;   dstOff = 0;   t -= 4608; }
  int Ct = C >> 5;
  int bx = t % Ct, by = t / Ct;
  __shared__ float tt[32][33];
  int tx = threadIdx.x & 31, ty = threadIdx.x >> 5;  // ty 0..7
  int c0 = bx * 32, r0 = by * 32;
#pragma unroll
  for (int k = 0; k < 4; ++k) {
    int r = r0 + ty + k * 8;
    tt[ty + k * 8][tx] = src[(size_t)r * C + c0 + tx];
  }
  __syncthreads();
#pragma unroll
  for (int k = 0; k < 4; ++k) {
    int c = c0 + ty + k * 8;
    dst[(size_t)(dstOff + c) * R + r0 + tx] = f2bf(tt[tx][ty + k * 8]);
  }
}

// ---------------- V transpose: qkv[b,j,1536+g*64+d] -> vT[(b*12+g)*64+d][j] ----------------
__global__ __launch_bounds__(256) void transpose_v_kernel(const unsigned short* __restrict__ qkv,
                                                          unsigned short* __restrict__ vT) {
  __shared__ unsigned short t[32][33];
  int tx = threadIdx.x & 31, ty = threadIdx.x >> 5;
  int j0 = blockIdx.x * 32, d0 = blockIdx.y * 32;
  int bg = blockIdx.z;
  int b = bg / kH, g = bg % kH;
#pragma unroll
  for (int k = 0; k < 4; ++k) {
    int j = j0 + ty + k * 8;
    t[ty + k * 8][tx] = qkv[(size_t)(b * kN + j) * kQKV + 1536 + g * 64 + d0 + tx];
  }
  __syncthreads();
#pragma unroll
  for (int k = 0; k < 4; ++k) {
    int d = d0 + ty + k * 8;
    vT[((size_t)(b * kH + g) * kDh + d) * kN + j0 + tx] = t[tx][ty + k * 8];
  }
}

// ---------------- GEMM: A[M,K]bf16 x Bt[N,K]bf16 -> epilogue ----------------
// EPI 0: C=bf16 plain; EPI 1: bf16 gelu(acc+bias); EPI 2: resid = (acc+bias)*scl + resid (f32)
template <int EPI>
__global__ __launch_bounds__(256) void gemm_kernel(const unsigned short* __restrict__ A,
                                                   const unsigned short* __restrict__ Bt,
                                                   const float* __restrict__ bias,
                                                   const float* __restrict__ scl,
                                                   float* __restrict__ resid,
                                                   unsigned short* __restrict__ C,
                                                   int K, int ldc) {
  __shared__ __align__(16) unsigned short lA[128 * 64];
  __shared__ __align__(16) unsigned short lB[128 * 64];
  int tid = threadIdx.x, wid = tid >> 6, lane = tid & 63;
  // XCD-aware bijective chunked swizzle (all grids have nwg % 8 == 0)
  int gx = gridDim.x;
  int nwg = gx * gridDim.y;
  int orig = blockIdx.y * gx + blockIdx.x;
  int chunk = nwg >> 3;
  int wg = (orig & 7) * chunk + (orig >> 3);
  int bx = wg % gx, by = wg / gx;
  int row0 = by * 128, col0 = bx * 128;
  int wr = wid >> 1, wc = wid & 1;
  f32x4 zero = {0.f, 0.f, 0.f, 0.f};
  f32x4 acc[4][4];
#pragma unroll
  for (int m = 0; m < 4; ++m)
#pragma unroll
    for (int n = 0; n < 4; ++n) acc[m][n] = zero;

  for (int kt = 0; kt < K; kt += 64) {
    __syncthreads();
#pragma unroll
    for (int t = 0; t < 4; ++t) {
      int cbase = wid * 256 + t * 64;
      int c = cbase + lane;
      int r = c >> 3, slot = c & 7;
      int k8 = slot ^ (r & 7);  // source-swizzle so LDS holds XOR-swizzled layout
      gload_lds16(&A[(size_t)(row0 + r) * K + kt + k8 * 8], &lA[cbase * 8]);
      gload_lds16(&Bt[(size_t)(col0 + r) * K + kt + k8 * 8], &lB[cbase * 8]);
    }
    __syncthreads();
#pragma unroll
    for (int kk = 0; kk < 2; ++kk) {
      bf16x8 af[4], bfr[4];
      int kslot = kk * 4 + (lane >> 4);
#pragma unroll
      for (int m = 0; m < 4; ++m) {
        int r = wr * 64 + m * 16 + (lane & 15);
        af[m] = *reinterpret_cast<const bf16x8*>(&lA[r * 64 + ((kslot ^ (r & 7)) << 3)]);
      }
#pragma unroll
      for (int n = 0; n < 4; ++n) {
        int r = wc * 64 + n * 16 + (lane & 15);
        bfr[n] = *reinterpret_cast<const bf16x8*>(&lB[r * 64 + ((kslot ^ (r & 7)) << 3)]);
      }
#pragma unroll
      for (int m = 0; m < 4; ++m)
#pragma unroll
        for (int n = 0; n < 4; ++n) acc[m][n] = mfma16x16x32(af[m], bfr[n], acc[m][n]);
    }
  }
#pragma unroll
  for (int m = 0; m < 4; ++m)
#pragma unroll
    for (int n = 0; n < 4; ++n)
#pragma unroll
      for (int r4 = 0; r4 < 4; ++r4) {
        int row = row0 + wr * 64 + m * 16 + ((lane >> 4) << 2) + r4;
        int col = col0 + wc * 64 + n * 16 + (lane & 15);
        float v = acc[m][n][r4];
        if (EPI == 0) {
          C[(size_t)row * ldc + col] = f2bf(v);
        } else if (EPI == 1) {
          v += bias[col];
          v = 0.5f * v * (1.f + erff(v * 0.70710678118654752f));
          C[(size_t)row * ldc + col] = f2bf(v);
        } else {
          v = (v + bias[col]) * scl[col];
          size_t idx = (size_t)row * kDim + col;
          resid[idx] = resid[idx] + v;
        }
      }
}

// ---------------- QK^T raw per-head scores -> dots bf16, layout [b][i][j][h16] ----------------
// h slots 12..15 are zero. LDS-staged for fully coalesced dwordx4 global writes.
__global__ __launch_bounds__(256) void dots_kernel(const unsigned short* __restrict__ qkv,
                                                   unsigned short* __restrict__ dots,
                                                   int i0, int IC) {
  constexpr int TROW = 24;  // ushorts per (i,j) slot: 16 h + 8 pad (48B, 16B-aligned)
  __shared__ __align__(16) unsigned short T[32 * 32 * TROW];  // 48KB
  int tid = threadIdx.x, wid = tid >> 6, lane = tid & 63;
  int kg = lane >> 4, l15 = lane & 15;
  int j0 = blockIdx.x * 32;
  int il0 = blockIdx.y * 32;
  int b = blockIdx.z;
  // zero h-slots 12..15
  for (int idx = tid; idx < 2048; idx += 256) {
    int pos = idx >> 1;
    *(unsigned int*)&T[pos * TROW + 12 + (idx & 1) * 2] = 0u;
  }
  f32x4 zero = {0.f, 0.f, 0.f, 0.f};
#pragma unroll
  for (int rep = 0; rep < 3; ++rep) {
    int h = rep * 4 + wid;
    f32x4 acc[2][2];
    acc[0][0] = zero; acc[0][1] = zero; acc[1][0] = zero; acc[1][1] = zero;
#pragma unroll
    for (int kk = 0; kk < 2; ++kk) {
      bf16x8 aq[2], bk[2];
#pragma unroll
      for (int m = 0; m < 2; ++m) {
        int tok = i0 + il0 + m * 16 + l15;
        aq[m] = *reinterpret_cast<const bf16x8*>(
            &qkv[(size_t)(b * kN + tok) * kQKV + h * 64 + kk * 32 + kg * 8]);
      }
#pragma unroll
      for (int n = 0; n < 2; ++n) {
        int tj = j0 + n * 16 + l15;
        bk[n] = *reinterpret_cast<const bf16x8*>(
            &qkv[(size_t)(b * kN + tj) * kQKV + 768 + h * 64 + kk * 32 + kg * 8]);
      }
#pragma unroll
      for (int m = 0; m < 2; ++m)
#pragma unroll
        for (int n = 0; n < 2; ++n) acc[m][n] = mfma16x16x32(aq[m], bk[n], acc[m][n]);
    }
#pragma unroll
    for (int m = 0; m < 2; ++m)
#pragma unroll
      for (int n = 0; n < 2; ++n)
#pragma unroll
        for (int r = 0; r < 4; ++r)
          T[((m * 16 + kg * 4 + r) * 32 + n * 16 + l15) * TROW + h] = f2bf(acc[m][n][r]);
  }
  __syncthreads();
  // coalesced write-out: 2048 chunks of 16B
#pragma unroll
  for (int k = 0; k < 8; ++k) {
    int c = tid + k * 256;
    int pos = c >> 1, half = c & 1;
    int ii = pos >> 5, jj = pos & 31;
    *(f32x4*)&dots[((size_t)(b * IC + il0 + ii) * kN + j0 + jj) * 16 + half * 8] =
        *(const f32x4*)&T[pos * TROW + half * 8];
  }
}

// ---------------- MFMA premix + softmax (no-max+clamp) + MFMA postmix -> p bf16 ----------------
// dots layout [b][i][j][h16]; pbuf layout [b][g2][i][j] (unchanged for pv).
__global__ __launch_bounds__(256) void softmax_mix_kernel(const unsigned short* __restrict__ dots,
                                                          const float* __restrict__ pre,
                                                          const float* __restrict__ post,
                                                          unsigned short* __restrict__ pbuf,
                                                          int IC) {
  constexpr int EROW = 24;  // ushorts per j row of E (16 g + 8 pad, 16B-aligned)
  __shared__ __align__(16) unsigned short E[1024 * EROW];   // 48KB
  __shared__ __align__(16) unsigned short preA[16 * 32];
  __shared__ __align__(16) unsigned short postA[16 * 32];
  __shared__ float red[4][16];
  __shared__ float lgs[16];
  int tid = threadIdx.x, wid = tid >> 6, lane = tid & 63;
  int kg = lane >> 4, l15 = lane & 15;
  int i = blockIdx.x, b = blockIdx.y;
  // build preA[m=g][k=h] = pre[h][g] * 0.125, zero-padded
  for (int idx = tid; idx < 512; idx += 256) {
    int m = idx >> 5, k = idx & 31;
    preA[idx] = f2bf((m < 12 && k < 12) ? pre[k * 12 + m] * 0.125f : 0.f);
  }
  __syncthreads();
  bf16x8 preF = *(const bf16x8*)&preA[l15 * 32 + kg * 8];
  const unsigned short* drow = dots + (size_t)(b * IC + i) * kN * 16;
  f32x4 zero = {0.f, 0.f, 0.f, 0.f};
  bf16x8 zfrag = {0, 0, 0, 0, 0, 0, 0, 0};
  float psum[4] = {0.f, 0.f, 0.f, 0.f};
  // pass A: premix via MFMA, exp, stash E[j][g], accumulate psum
#pragma unroll
  for (int grp = 0; grp < 16; ++grp) {
    int j = wid * 256 + grp * 16 + l15;
    bf16x8 bfrag = (kg < 2) ? *(const bf16x8*)&drow[(size_t)j * 16 + kg * 8] : zfrag;
    f32x4 d = mfma16x16x32(preF, bfrag, zero);  // D[g=kg*4+r][j=l15]
    float ee[4];
#pragma unroll
    for (int r = 0; r < 4; ++r) {
      float dc = fminf(fmaxf(d[r], -15.f), 15.f);
      ee[r] = (kg == 3) ? 0.f : __expf(dc);
      psum[r] += ee[r];
    }
    unsigned int w0, w1;
    asm("v_cvt_pk_bf16_f32 %0, %1, %2" : "=v"(w0) : "v"(ee[0]), "v"(ee[1]));
    asm("v_cvt_pk_bf16_f32 %0, %1, %2" : "=v"(w1) : "v"(ee[2]), "v"(ee[3]));
    *(unsigned int*)&E[j * EROW + kg * 4] = w0;
    *(unsigned int*)&E[j * EROW + kg * 4 + 2] = w1;
  }
  // reduce psum over 16 cols (l15 lanes), then 4 waves
#pragma unroll
  for (int r = 0; r < 4; ++r) {
    psum[r] += __shfl_xor(psum[r], 1);
    psum[r] += __shfl_xor(psum[r], 2);
    psum[r] += __shfl_xor(psum[r], 4);
    psum[r] += __shfl_xor(psum[r], 8);
  }
  if (l15 == 0) {
#pragma unroll
    for (int r = 0; r < 4; ++r) red[wid][kg * 4 + r] = psum[r];
  }
  __syncthreads();
  if (tid < 16) {
    float s = red[0][tid] + red[1][tid] + red[2][tid] + red[3][tid];
    lgs[tid] = (tid < 12) ? 1.f / s : 0.f;
  }
  __syncthreads();
  // build postA[m=g2][k=g] = post[g][g2] * lg[g], zero-padded
  for (int idx = tid; idx < 512; idx += 256) {
    int m = idx >> 5, k = idx & 31;
    postA[idx] = f2bf((m < 12 && k < 12) ? post[k * 12 + m] * lgs[k] : 0.f);
  }
  __syncthreads();
  bf16x8 postF = *(const bf16x8*)&postA[l15 * 32 + kg * 8];
  // pass B: postmix via MFMA, write p
#pragma unroll
  for (int grp = 0; grp < 16; ++grp) {
    int j = wid * 256 + grp * 16 + l15;
    bf16x8 efrag = (kg < 2) ? *(const bf16x8*)&E[j * EROW + kg * 8] : zfrag;
    f32x4 d2 = mfma16x16x32(postF, efrag, zero);  // D[g2=kg*4+r][j=l15]
    if (kg < 3) {
#pragma unroll
      for (int r = 0; r < 4; ++r) {
        int g2 = kg * 4 + r;
        pbuf[((size_t)(b * kH + g2) * IC + i) * kN + j] = f2bf(d2[r]);
      }
    }
  }
}

// ---------------- PV: out[b,i,g*64+d] = sum_j p[b,g,i,j] * v[b,g,j,d] (32 i-rows/block) --------
__global__ __launch_bounds__(256) void pv_kernel(const unsigned short* __restrict__ pbuf,
                                                 const unsigned short* __restrict__ vT,
                                                 unsigned short* __restrict__ attn_out,
                                                 int i0, int IC) {
  int tid = threadIdx.x, wid = tid >> 6, lane = tid & 63;
  int kg = lane >> 4, l15 = lane & 15;
  int i32 = blockIdx.x * 32;
  int g = blockIdx.y, b = blockIdx.z;
  const unsigned short* prow = pbuf + (size_t)(b * kH + g) * IC * kN;
  const unsigned short* vrow = vT + (size_t)(b * kH + g) * kDh * kN;
  f32x4 zero = {0.f, 0.f, 0.f, 0.f};
  f32x4 acc[2][4];
#pragma unroll
  for (int half = 0; half < 2; ++half)
#pragma unroll
    for (int n = 0; n < 4; ++n) acc[half][n] = zero;
#pragma unroll
  for (int s = 0; s < 8; ++s) {
    int kt = (wid * 8 + s) * 32 + kg * 8;
    bf16x8 ap[2];
#pragma unroll
    for (int half = 0; half < 2; ++half)
      ap[half] = *reinterpret_cast<const bf16x8*>(&prow[(size_t)(i32 + half * 16 + l15) * kN + kt]);
#pragma unroll
    for (int n = 0; n < 4; ++n) {
      bf16x8 bv = *reinterpret_cast<const bf16x8*>(&vrow[(size_t)(n * 16 + l15) * kN + kt]);
#pragma unroll
      for (int half = 0; half < 2; ++half)
        acc[half][n] = mfma16x16x32(ap[half], bv, acc[half][n]);
    }
  }
  __shared__ float red[3][32][64];
  if (wid > 0) {
#pragma unroll
    for (int half = 0; half < 2; ++half)
#pragma unroll
      for (int n = 0; n < 4; ++n)
#pragma unroll
        for (int r = 0; r < 4; ++r)
          red[wid - 1][half * 16 + kg * 4 + r][n * 16 + l15] = acc[half][n][r];
  }
  __syncthreads();
  if (wid == 0) {
#pragma unroll
    for (int half = 0; half < 2; ++half)
#pragma unroll
      for (int n = 0; n < 4; ++n)
#pragma unroll
        for (int r = 0; r < 4; ++r) {
          int rr = half * 16 + kg * 4 + r, cc = n * 16 + l15;
          float v = acc[half][n][r] + red[0][rr][cc] + red[1][rr][cc] + red[2][rr][cc];
          int tok = i0 + i32 + rr;
          attn_out[(size_t)(b * kN + tok) * kDim + g * kDh + cc] = f2bf(v);
        }
  }
}

extern "C" void kernel_launch(void* const* d_in, const int* in_sizes, int n_in,
                              void* d_out, int out_size, void* d_ws, size_t ws_size,
                              hipStream_t stream) {
  (void)in_sizes; (void)n_in; (void)out_size;
  const float* x     = (const float*)d_in[0];
  const float* ln1_g = (const float*)d_in[1];
  const float* ln1_b = (const float*)d_in[2];
  const float* Wq    = (const float*)d_in[3];
  const float* Wkv   = (const float*)d_in[4];
  const float* pre   = (const float*)d_in[5];
  const float* post  = (const float*)d_in[6];
  const float* Wo    = (const float*)d_in[7];
  const float* bo    = (const float*)d_in[8];
  const float* s1    = (const float*)d_in[9];
  const float* ln2_g = (const float*)d_in[10];
  const float* ln2_b = (const float*)d_in[11];
  const float* W1    = (const float*)d_in[12];
  const float* b1    = (const float*)d_in[13];
  const float* W2    = (const float*)d_in[14];
  const float* b2    = (const float*)d_in[15];
  const float* s2    = (const float*)d_in[16];
  float* xo = (float*)d_out;

  char* ws = (char*)d_ws;
  size_t off = 0;
  auto alloc = [&](size_t bytes) -> void* {
    void* p = ws + off;
    off += (bytes + 255) & ~(size_t)255;
    return p;
  };
  unsigned short* h_buf   = (unsigned short*)alloc((size_t)kRows * kDim * 2);
  unsigned short* qkv     = (unsigned short*)alloc((size_t)kRows * kQKV * 2);
  unsigned short* vT      = (unsigned short*)alloc((size_t)kB * kH * kDh * kN * 2);
  unsigned short* attnout = (unsigned short*)alloc((size_t)kRows * kDim * 2);
  unsigned short* mid     = (unsigned short*)alloc((size_t)kRows * kMlp * 2);
  unsigned short* wqkvT   = (unsigned short*)alloc((size_t)kQKV * kDim * 2);
  unsigned short* woT     = (unsigned short*)alloc((size_t)kDim * kDim * 2);
  unsigned short* w1T     = (unsigned short*)alloc((size_t)kMlp * kDim * 2);
  unsigned short* w2T     = (unsigned short*)alloc((size_t)kDim * kMlp * 2);

  size_t base = off;
  // per-i-row bytes: dots [b][i][j][16] bf16 = 8*1024*16*2 = 262144; pbuf = 8*12*1024*2 = 196608
  int IC = 1024;
  while (IC > 32 && base + (size_t)IC * (262144 + 196608) + 1024 > ws_size) IC >>= 1;
  unsigned short* dots = (unsigned short*)alloc((size_t)kB * IC * kN * 16 * 2);
  unsigned short* pbuf = (unsigned short*)alloc((size_t)kB * kH * IC * kN * 2);

  hipMemcpyAsync(xo, x, (size_t)kRows * kDim * 4, hipMemcpyDeviceToDevice, stream);

  for (int L = 0; L < kDepth; ++L) {
    // --- attention block ---
    ln_kernel<<<kRows, 256, 0, stream>>>(xo, ln1_g + L * kDim, ln1_b + L * kDim, h_buf);
    transpose_all<<<6912, 256, 0, stream>>>(Wq, Wkv, Wo, W1, W2, wqkvT, woT, w1T, w2T, L);

    gemm_kernel<0><<<dim3(kQKV / 128, kRows / 128), 256, 0, stream>>>(
        h_buf, wqkvT, nullptr, nullptr, nullptr, qkv, kDim, kQKV);
    transpose_v_kernel<<<dim3(kN / 32, kDh / 32, kB * kH), 256, 0, stream>>>(qkv, vT);

    for (int i0 = 0; i0 < kN; i0 += IC) {
      dots_kernel<<<dim3(kN / 32, IC / 32, kB), 256, 0, stream>>>(qkv, dots, i0, IC);
      softmax_mix_kernel<<<dim3(IC, kB), 256, 0, stream>>>(
          dots, pre + L * 144, post + L * 144, pbuf, IC);
      pv_kernel<<<dim3(IC / 32, kH, kB), 256, 0, stream>>>(pbuf, vT, attnout, i0, IC);
    }
    gemm_kernel<2><<<dim3(kDim / 128, kRows / 128), 256, 0, stream>>>(
        attnout, woT, bo + L * kDim, s1 + L * kDim, xo, nullptr, kDim, kDim);

    // --- MLP block ---
    ln_kernel<<<kRows, 256, 0, stream>>>(xo, ln2_g + L * kDim, ln2_b + L * kDim, h_buf);
    gemm_kernel<1><<<dim3(kMlp / 128, kRows / 128), 256, 0, stream>>>(
        h_buf, w1T, b1 + L * kMlp, nullptr, nullptr, mid, kDim, kMlp);
    gemm_kernel<2><<<dim3(kDim / 128, kRows / 128), 256, 0, stream>>>(
        mid, w2T, b2 + L * kDim, s2 + L * kDim, xo, nullptr, kMlp, kDim);
  }
}

// Round 14
// 3421.043 us; speedup vs baseline: 1.3246x; 1.0329x over previous
//
#include <hip/hip_runtime.h>

constexpr int kDepth = 6;
constexpr int kB = 8;
constexpr int kN = 1024;
constexpr int kDim = 768;
constexpr int kH = 12;
constexpr int kDh = 64;
constexpr int kMlp = 3072;
constexpr int kRows = kB * kN;   // 8192
constexpr int kQKV = 2304;       // q(768) k(768) v(768)

typedef __attribute__((ext_vector_type(4))) float f32x4;
typedef __attribute__((ext_vector_type(8))) short bf16x8;

__device__ __forceinline__ f32x4 mfma16x16x32(bf16x8 a, bf16x8 b, f32x4 c) {
  return __builtin_amdgcn_mfma_f32_16x16x32_bf16(a, b, c, 0, 0, 0);
}

__device__ __forceinline__ unsigned short f2bf(float f) {
  unsigned int u = __builtin_bit_cast(unsigned int, f);
  u = u + 0x7FFFu + ((u >> 16) & 1u);
  return (unsigned short)(u >> 16);
}

__device__ __forceinline__ float bf2f(unsigned short u) {
  return __builtin_bit_cast(float, (unsigned int)u << 16);
}

__device__ __forceinline__ void gload_lds16(const void* g, void* l) {
  __builtin_amdgcn_global_load_lds((__attribute__((address_space(1))) void*)g,
                                   (__attribute__((address_space(3))) void*)l,
                                   16, 0, 0);
}

// ---------------- LayerNorm: f32 in -> bf16 out ----------------
__global__ __launch_bounds__(256) void ln_kernel(const float* __restrict__ x,
                                                 const float* __restrict__ gamma,
                                                 const float* __restrict__ beta,
                                                 unsigned short* __restrict__ out) {
  int row = blockIdx.x, tid = threadIdx.x;
  const float* xr = x + (size_t)row * kDim;
  float v0 = xr[tid], v1 = xr[tid + 256], v2 = xr[tid + 512];
  float s = v0 + v1 + v2;
  float q = v0 * v0 + v1 * v1 + v2 * v2;
#pragma unroll
  for (int o = 32; o >= 1; o >>= 1) {
    s += __shfl_xor(s, o);
    q += __shfl_xor(q, o);
  }
  __shared__ float ss[4], sq[4];
  int wid = tid >> 6, lane = tid & 63;
  if (lane == 0) { ss[wid] = s; sq[wid] = q; }
  __syncthreads();
  s = ss[0] + ss[1] + ss[2] + ss[3];
  q = sq[0] + sq[1] + sq[2] + sq[3];
  float mean = s * (1.0f / kDim);
  float var = q * (1.0f / kDim) - mean * mean;
  float rstd = rsqrtf(var + 1e-5f);
  unsigned short* orow = out + (size_t)row * kDim;
  orow[tid]       = f2bf((v0 - mean) * rstd * gamma[tid]       + beta[tid]);
  orow[tid + 256] = f2bf((v1 - mean) * rstd * gamma[tid + 256] + beta[tid + 256]);
  orow[tid + 512] = f2bf((v2 - mean) * rstd * gamma[tid + 512] + beta[tid + 512]);
}

// ---------------- Batched weight transpose: all 5 matrices of one layer ----------------
__global__ __launch_bounds__(256) void transpose_all(const float* __restrict__ Wq,
                                                     const float* __restrict__ Wkv,
                                                     const float* __restrict__ Wo,
                                                     const float* __restrict__ W1,
                                                     const float* __restrict__ W2,
                                                     unsigned short* __restrict__ wqkvT,
                                                     unsigned short* __restrict__ woT,
                                                     unsigned short* __restrict__ w1T,
                                                     unsigned short* __restrict__ w2T,
                                                     int L) {
  int t = blockIdx.x;
  const float* src;
  unsigned short* dst;
  int R, C, dstOff;
  if (t < 576)       { src = Wq  + (size_t)L * 768 * 768;  R = 768;  C = 768;  dst = wqkvT; dstOff = 0;   }
  else if (t < 1728) { src = Wkv + (size_t)L * 768 * 1536; R = 768;  C = 1536; dst = wqkvT; dstOff = 768; t -= 576; }
  else if (t < 2304) { src = Wo  + (size_t)L * 768 * 768;  R = 768;  C = 768;  dst = woT;   dstOff = 0;   t -= 1728; }
  else if (t < 4608) { src = W1  + (size_t)L * 768 * 3072; R = 768;  C = 3072; dst = w1T;   dstOff = 0;   t -= 2304; }
  else               { src = W2  + (size_t)L * 3072 * 768; R = 3072; C = 768;  dst = w2T;   dstOff = 0;   t -= 4608; }
  int Ct = C >> 5;
  int bx = t % Ct, by = t / Ct;
  __shared__ float tt[32][33];
  int tx = threadIdx.x & 31, ty = threadIdx.x >> 5;  // ty 0..7
  int c0 = bx * 32, r0 = by * 32;
#pragma unroll
  for (int k = 0; k < 4; ++k) {
    int r = r0 + ty + k * 8;
    tt[ty + k * 8][tx] = src[(size_t)r * C + c0 + tx];
  }
  __syncthreads();
#pragma unroll
  for (int k = 0; k < 4; ++k) {
    int c = c0 + ty + k * 8;
    dst[(size_t)(dstOff + c) * R + r0 + tx] = f2bf(tt[tx][ty + k * 8]);
  }
}

// ---------------- GEMM: A[M,K]bf16 x Bt[N,K]bf16 -> epilogue ----------------
// EPI 0: C=bf16 plain; EPI 1: bf16 gelu(acc+bias); EPI 2: resid += (acc+bias)*scl
// EPI 3: QKV fused: cols<1536 -> qkv bf16; cols>=1536 -> vT[(b*12+g)*64+d][j] packed stores
template <int EPI, int BK>
__global__ __launch_bounds__(256) void gemm_kernel(const unsigned short* __restrict__ A,
                                                   const unsigned short* __restrict__ Bt,
                                                   const float* __restrict__ bias,
                                                   const float* __restrict__ scl,
                                                   float* __restrict__ resid,
                                                   unsigned short* __restrict__ C,
                                                   unsigned short* __restrict__ vT,
                                                   int K, int ldc) {
  __shared__ __align__(16) unsigned short lA[128 * BK];
  __shared__ __align__(16) unsigned short lB[128 * BK];
  int tid = threadIdx.x, wid = tid >> 6, lane = tid & 63;
  // XCD-aware bijective chunked swizzle (all grids have nwg % 8 == 0)
  int gx = gridDim.x;
  int nwg = gx * gridDim.y;
  int orig = blockIdx.y * gx + blockIdx.x;
  int chunk = nwg >> 3;
  int wg = (orig & 7) * chunk + (orig >> 3);
  int bx = wg % gx, by = wg / gx;
  int row0 = by * 128, col0 = bx * 128;
  int wr = wid >> 1, wc = wid & 1;
  f32x4 zero = {0.f, 0.f, 0.f, 0.f};
  f32x4 acc[4][4];
#pragma unroll
  for (int m = 0; m < 4; ++m)
#pragma unroll
    for (int n = 0; n < 4; ++n) acc[m][n] = zero;

  constexpr int SL = BK / 8;                 // 16B slots per row
  constexpr int PT = (128 * SL) / 256;       // chunks per thread per matrix

  for (int kt = 0; kt < K; kt += BK) {
    __syncthreads();
#pragma unroll
    for (int t = 0; t < PT; ++t) {
      int c = t * 256 + tid;
      int r = c / SL, slot = c % SL;
      int k8 = (slot & ~7) | ((slot & 7) ^ (r & 7));  // source-swizzle (low 3 bits)
      gload_lds16(&A[(size_t)(row0 + r) * K + kt + k8 * 8], &lA[c * 8]);
      gload_lds16(&Bt[(size_t)(col0 + r) * K + kt + k8 * 8], &lB[c * 8]);
    }
    __syncthreads();
#pragma unroll
    for (int kk = 0; kk < BK / 32; ++kk) {
      bf16x8 af[4], bfr[4];
      int kslot = kk * 4 + (lane >> 4);
#pragma unroll
      for (int m = 0; m < 4; ++m) {
        int r = wr * 64 + m * 16 + (lane & 15);
        int koff = ((kslot & ~7) | ((kslot & 7) ^ (r & 7))) << 3;
        af[m] = *reinterpret_cast<const bf16x8*>(&lA[r * BK + koff]);
      }
#pragma unroll
      for (int n = 0; n < 4; ++n) {
        int r = wc * 64 + n * 16 + (lane & 15);
        int koff = ((kslot & ~7) | ((kslot & 7) ^ (r & 7))) << 3;
        bfr[n] = *reinterpret_cast<const bf16x8*>(&lB[r * BK + koff]);
      }
#pragma unroll
      for (int m = 0; m < 4; ++m)
#pragma unroll
        for (int n = 0; n < 4; ++n) acc[m][n] = mfma16x16x32(af[m], bfr[n], acc[m][n]);
    }
  }

  if (EPI == 3 && col0 >= 1536) {
    // V-region tile: write straight to vT (transpose fused); 4 consecutive j per lane -> u64
#pragma unroll
    for (int m = 0; m < 4; ++m)
#pragma unroll
      for (int n = 0; n < 4; ++n) {
        int row = row0 + wr * 64 + m * 16 + ((lane >> 4) << 2);
        int col = col0 + wc * 64 + n * 16 + (lane & 15);
        int d = col - 1536;
        int b = row >> 10, j = row & 1023;
        int g = d >> 6, dd = d & 63;
        unsigned short tmp[4];
#pragma unroll
        for (int r4 = 0; r4 < 4; ++r4) tmp[r4] = f2bf(acc[m][n][r4]);
        *(unsigned long long*)&vT[((size_t)((b * 12 + g) * 64 + dd)) * kN + j] =
            *(unsigned long long*)tmp;
      }
    return;
  }
#pragma unroll
  for (int m = 0; m < 4; ++m)
#pragma unroll
    for (int n = 0; n < 4; ++n)
#pragma unroll
      for (int r4 = 0; r4 < 4; ++r4) {
        int row = row0 + wr * 64 + m * 16 + ((lane >> 4) << 2) + r4;
        int col = col0 + wc * 64 + n * 16 + (lane & 15);
        float v = acc[m][n][r4];
        if (EPI == 0 || EPI == 3) {
          C[(size_t)row * ldc + col] = f2bf(v);
        } else if (EPI == 1) {
          v += bias[col];
          v = 0.5f * v * (1.f + erff(v * 0.70710678118654752f));
          C[(size_t)row * ldc + col] = f2bf(v);
        } else {
          v = (v + bias[col]) * scl[col];
          size_t idx = (size_t)row * kDim + col;
          resid[idx] = resid[idx] + v;
        }
      }
}

// ---------------- QK^T raw per-head scores -> dots bf16, layout [b][i][j][h16] ----------------
// h slots 12..15 are zero. LDS-staged for fully coalesced dwordx4 global writes.
__global__ __launch_bounds__(256) void dots_kernel(const unsigned short* __restrict__ qkv,
                                                   unsigned short* __restrict__ dots,
                                                   int i0, int IC) {
  constexpr int TROW = 24;  // ushorts per (i,j) slot: 16 h + 8 pad (48B, 16B-aligned)
  __shared__ __align__(16) unsigned short T[32 * 32 * TROW];  // 48KB
  int tid = threadIdx.x, wid = tid >> 6, lane = tid & 63;
  int kg = lane >> 4, l15 = lane & 15;
  int j0 = blockIdx.x * 32;
  int il0 = blockIdx.y * 32;
  int b = blockIdx.z;
  // zero h-slots 12..15
  for (int idx = tid; idx < 2048; idx += 256) {
    int pos = idx >> 1;
    *(unsigned int*)&T[pos * TROW + 12 + (idx & 1) * 2] = 0u;
  }
  f32x4 zero = {0.f, 0.f, 0.f, 0.f};
#pragma unroll
  for (int rep = 0; rep < 3; ++rep) {
    int h = rep * 4 + wid;
    f32x4 acc[2][2];
    acc[0][0] = zero; acc[0][1] = zero; acc[1][0] = zero; acc[1][1] = zero;
#pragma unroll
    for (int kk = 0; kk < 2; ++kk) {
      bf16x8 aq[2], bk[2];
#pragma unroll
      for (int m = 0; m < 2; ++m) {
        int tok = i0 + il0 + m * 16 + l15;
        aq[m] = *reinterpret_cast<const bf16x8*>(
            &qkv[(size_t)(b * kN + tok) * kQKV + h * 64 + kk * 32 + kg * 8]);
      }
#pragma unroll
      for (int n = 0; n < 2; ++n) {
        int tj = j0 + n * 16 + l15;
        bk[n] = *reinterpret_cast<const bf16x8*>(
            &qkv[(size_t)(b * kN + tj) * kQKV + 768 + h * 64 + kk * 32 + kg * 8]);
      }
#pragma unroll
      for (int m = 0; m < 2; ++m)
#pragma unroll
        for (int n = 0; n < 2; ++n) acc[m][n] = mfma16x16x32(aq[m], bk[n], acc[m][n]);
    }
#pragma unroll
    for (int m = 0; m < 2; ++m)
#pragma unroll
      for (int n = 0; n < 2; ++n)
#pragma unroll
        for (int r = 0; r < 4; ++r)
          T[((m * 16 + kg * 4 + r) * 32 + n * 16 + l15) * TROW + h] = f2bf(acc[m][n][r]);
  }
  __syncthreads();
  // coalesced write-out: 2048 chunks of 16B
#pragma unroll
  for (int k = 0; k < 8; ++k) {
    int c = tid + k * 256;
    int pos = c >> 1, half = c & 1;
    int ii = pos >> 5, jj = pos & 31;
    *(f32x4*)&dots[((size_t)(b * IC + il0 + ii) * kN + j0 + jj) * 16 + half * 8] =
        *(const f32x4*)&T[pos * TROW + half * 8];
  }
}

// ---------------- MFMA premix + softmax (no-max+clamp) + MFMA postmix -> p bf16 ----------------
// dots layout [b][i][j][h16]; pbuf layout [b][g2][i][j] (unchanged for pv).
__global__ __launch_bounds__(256) void softmax_mix_kernel(const unsigned short* __restrict__ dots,
                                                          const float* __restrict__ pre,
                                                          const float* __restrict__ post,
                                                          unsigned short* __restrict__ pbuf,
                                                          int IC) {
  constexpr int EROW = 24;  // ushorts per j row of E (16 g + 8 pad, 16B-aligned)
  __shared__ __align__(16) unsigned short E[1024 * EROW];   // 48KB
  __shared__ __align__(16) unsigned short preA[16 * 32];
  __shared__ __align__(16) unsigned short postA[16 * 32];
  __shared__ float red[4][16];
  __shared__ float lgs[16];
  int tid = threadIdx.x, wid = tid >> 6, lane = tid & 63;
  int kg = lane >> 4, l15 = lane & 15;
  int i = blockIdx.x, b = blockIdx.y;
  // build preA[m=g][k=h] = pre[h][g] * 0.125, zero-padded
  for (int idx = tid; idx < 512; idx += 256) {
    int m = idx >> 5, k = idx & 31;
    preA[idx] = f2bf((m < 12 && k < 12) ? pre[k * 12 + m] * 0.125f : 0.f);
  }
  __syncthreads();
  bf16x8 preF = *(const bf16x8*)&preA[l15 * 32 + kg * 8];
  const unsigned short* drow = dots + (size_t)(b * IC + i) * kN * 16;
  f32x4 zero = {0.f, 0.f, 0.f, 0.f};
  bf16x8 zfrag = {0, 0, 0, 0, 0, 0, 0, 0};
  float psum[4] = {0.f, 0.f, 0.f, 0.f};
  // pass A: premix via MFMA, exp, stash E[j][g], accumulate psum
#pragma unroll
  for (int grp = 0; grp < 16; ++grp) {
    int j = wid * 256 + grp * 16 + l15;
    bf16x8 bfrag = (kg < 2) ? *(const bf16x8*)&drow[(size_t)j * 16 + kg * 8] : zfrag;
    f32x4 d = mfma16x16x32(preF, bfrag, zero);  // D[g=kg*4+r][j=l15]
    float ee[4];
#pragma unroll
    for (int r = 0; r < 4; ++r) {
      float dc = fminf(fmaxf(d[r], -15.f), 15.f);
      ee[r] = (kg == 3) ? 0.f : __expf(dc);
      psum[r] += ee[r];
    }
    unsigned int w0, w1;
    asm("v_cvt_pk_bf16_f32 %0, %1, %2" : "=v"(w0) : "v"(ee[0]), "v"(ee[1]));
    asm("v_cvt_pk_bf16_f32 %0, %1, %2" : "=v"(w1) : "v"(ee[2]), "v"(ee[3]));
    *(unsigned int*)&E[j * EROW + kg * 4] = w0;
    *(unsigned int*)&E[j * EROW + kg * 4 + 2] = w1;
  }
  // reduce psum over 16 cols (l15 lanes), then 4 waves
#pragma unroll
  for (int r = 0; r < 4; ++r) {
    psum[r] += __shfl_xor(psum[r], 1);
    psum[r] += __shfl_xor(psum[r], 2);
    psum[r] += __shfl_xor(psum[r], 4);
    psum[r] += __shfl_xor(psum[r], 8);
  }
  if (l15 == 0) {
#pragma unroll
    for (int r = 0; r < 4; ++r) red[wid][kg * 4 + r] = psum[r];
  }
  __syncthreads();
  if (tid < 16) {
    float s = red[0][tid] + red[1][tid] + red[2][tid] + red[3][tid];
    lgs[tid] = (tid < 12) ? 1.f / s : 0.f;
  }
  __syncthreads();
  // build postA[m=g2][k=g] = post[g][g2] * lg[g], zero-padded
  for (int idx = tid; idx < 512; idx += 256) {
    int m = idx >> 5, k = idx & 31;
    postA[idx] = f2bf((m < 12 && k < 12) ? post[k * 12 + m] * lgs[k] : 0.f);
  }
  __syncthreads();
  bf16x8 postF = *(const bf16x8*)&postA[l15 * 32 + kg * 8];
  // pass B: postmix via MFMA, write p
#pragma unroll
  for (int grp = 0; grp < 16; ++grp) {
    int j = wid * 256 + grp * 16 + l15;
    bf16x8 efrag = (kg < 2) ? *(const bf16x8*)&E[j * EROW + kg * 8] : zfrag;
    f32x4 d2 = mfma16x16x32(postF, efrag, zero);  // D[g2=kg*4+r][j=l15]
    if (kg < 3) {
#pragma unroll
      for (int r = 0; r < 4; ++r) {
        int g2 = kg * 4 + r;
        pbuf[((size_t)(b * kH + g2) * IC + i) * kN + j] = f2bf(d2[r]);
      }
    }
  }
}

// ---------------- PV: out[b,i,g*64+d] = sum_j p[b,g,i,j] * v[b,g,j,d] (32 i-rows/block) --------
__global__ __launch_bounds__(256) void pv_kernel(const unsigned short* __restrict__ pbuf,
                                                 const unsigned short* __restrict__ vT,
                                                 unsigned short* __restrict__ attn_out,
                                                 int i0, int IC) {
  int tid = threadIdx.x, wid = tid >> 6, lane = tid & 63;
  int kg = lane >> 4, l15 = lane & 15;
  int i32 = blockIdx.x * 32;
  int g = blockIdx.y, b = blockIdx.z;
  const unsigned short* prow = pbuf + (size_t)(b * kH + g) * IC * kN;
  const unsigned short* vrow = vT + (size_t)(b * kH + g) * kDh * kN;
  f32x4 zero = {0.f, 0.f, 0.f, 0.f};
  f32x4 acc[2][4];
#pragma unroll
  for (int half = 0; half < 2; ++half)
#pragma unroll
    for (int n = 0; n < 4; ++n) acc[half][n] = zero;
#pragma unroll
  for (int s = 0; s < 8; ++s) {
    int kt = (wid * 8 + s) * 32 + kg * 8;
    bf16x8 ap[2];
#pragma unroll
    for (int half = 0; half < 2; ++half)
      ap[half] = *reinterpret_cast<const bf16x8*>(&prow[(size_t)(i32 + half * 16 + l15) * kN + kt]);
#pragma unroll
    for (int n = 0; n < 4; ++n) {
      bf16x8 bv = *reinterpret_cast<const bf16x8*>(&vrow[(size_t)(n * 16 + l15) * kN + kt]);
#pragma unroll
      for (int half = 0; half < 2; ++half)
        acc[half][n] = mfma16x16x32(ap[half], bv, acc[half][n]);
    }
  }
  __shared__ float red[3][32][64];
  if (wid > 0) {
#pragma unroll
    for (int half = 0; half < 2; ++half)
#pragma unroll
      for (int n = 0; n < 4; ++n)
#pragma unroll
        for (int r = 0; r < 4; ++r)
          red[wid - 1][half * 16 + kg * 4 + r][n * 16 + l15] = acc[half][n][r];
  }
  __syncthreads();
  if (wid == 0) {
#pragma unroll
    for (int half = 0; half < 2; ++half)
#pragma unroll
      for (int n = 0; n < 4; ++n)
#pragma unroll
        for (int r = 0; r < 4; ++r) {
          int rr = half * 16 + kg * 4 + r, cc = n * 16 + l15;
          float v = acc[half][n][r] + red[0][rr][cc] + red[1][rr][cc] + red[2][rr][cc];
          int tok = i0 + i32 + rr;
          attn_out[(size_t)(b * kN + tok) * kDim + g * kDh + cc] = f2bf(v);
        }
  }
}

extern "C" void kernel_launch(void* const* d_in, const int* in_sizes, int n_in,
                              void* d_out, int out_size, void* d_ws, size_t ws_size,
                              hipStream_t stream) {
  (void)in_sizes; (void)n_in; (void)out_size;
  const float* x     = (const float*)d_in[0];
  const float* ln1_g = (const float*)d_in[1];
  const float* ln1_b = (const float*)d_in[2];
  const float* Wq    = (const float*)d_in[3];
  const float* Wkv   = (const float*)d_in[4];
  const float* pre   = (const float*)d_in[5];
  const float* post  = (const float*)d_in[6];
  const float* Wo    = (const float*)d_in[7];
  const float* bo    = (const float*)d_in[8];
  const float* s1    = (const float*)d_in[9];
  const float* ln2_g = (const float*)d_in[10];
  const float* ln2_b = (const float*)d_in[11];
  const float* W1    = (const float*)d_in[12];
  const float* b1    = (const float*)d_in[13];
  const float* W2    = (const float*)d_in[14];
  const float* b2    = (const float*)d_in[15];
  const float* s2    = (const float*)d_in[16];
  float* xo = (float*)d_out;

  char* ws = (char*)d_ws;
  size_t off = 0;
  auto alloc = [&](size_t bytes) -> void* {
    void* p = ws + off;
    off += (bytes + 255) & ~(size_t)255;
    return p;
  };
  unsigned short* h_buf   = (unsigned short*)alloc((size_t)kRows * kDim * 2);
  unsigned short* qkv     = (unsigned short*)alloc((size_t)kRows * kQKV * 2);
  unsigned short* vT      = (unsigned short*)alloc((size_t)kB * kH * kDh * kN * 2);
  unsigned short* attnout = (unsigned short*)alloc((size_t)kRows * kDim * 2);
  unsigned short* mid     = (unsigned short*)alloc((size_t)kRows * kMlp * 2);
  unsigned short* wqkvT   = (unsigned short*)alloc((size_t)kQKV * kDim * 2);
  unsigned short* woT     = (unsigned short*)alloc((size_t)kDim * kDim * 2);
  unsigned short* w1T     = (unsigned short*)alloc((size_t)kMlp * kDim * 2);
  unsigned short* w2T     = (unsigned short*)alloc((size_t)kDim * kMlp * 2);

  size_t base = off;
  // per-i-row bytes: dots [b][i][j][16] bf16 = 262144; pbuf = 196608
  int IC = 1024;
  while (IC > 32 && base + (size_t)IC * (262144 + 196608) + 1024 > ws_size) IC >>= 1;
  unsigned short* dots = (unsigned short*)alloc((size_t)kB * IC * kN * 16 * 2);
  unsigned short* pbuf = (unsigned short*)alloc((size_t)kB * kH * IC * kN * 2);

  hipMemcpyAsync(xo, x, (size_t)kRows * kDim * 4, hipMemcpyDeviceToDevice, stream);

  for (int L = 0; L < kDepth; ++L) {
    // --- attention block ---
    ln_kernel<<<kRows, 256, 0, stream>>>(xo, ln1_g + L * kDim, ln1_b + L * kDim, h_buf);
    transpose_all<<<6912, 256, 0, stream>>>(Wq, Wkv, Wo, W1, W2, wqkvT, woT, w1T, w2T, L);

    // QKV GEMM with fused V-transpose epilogue (V cols go straight to vT)
    gemm_kernel<3, 64><<<dim3(kQKV / 128, kRows / 128), 256, 0, stream>>>(
        h_buf, wqkvT, nullptr, nullptr, nullptr, qkv, vT, kDim, kQKV);

    for (int i0 = 0; i0 < kN; i0 += IC) {
      dots_kernel<<<dim3(kN / 32, IC / 32, kB), 256, 0, stream>>>(qkv, dots, i0, IC);
      softmax_mix_kernel<<<dim3(IC, kB), 256, 0, stream>>>(
          dots, pre + L * 144, post + L * 144, pbuf, IC);
      pv_kernel<<<dim3(IC / 32, kH, kB), 256, 0, stream>>>(pbuf, vT, attnout, i0, IC);
    }
    gemm_kernel<2, 128><<<dim3(kDim / 128, kRows / 128), 256, 0, stream>>>(
        attnout, woT, bo + L * kDim, s1 + L * kDim, xo, nullptr, nullptr, kDim, kDim);

    // --- MLP block ---
    ln_kernel<<<kRows, 256, 0, stream>>>(xo, ln2_g + L * kDim, ln2_b + L * kDim, h_buf);
    gemm_kernel<1, 64><<<dim3(kMlp / 128, kRows / 128), 256, 0, stream>>>(
        h_buf, w1T, b1 + L * kMlp, nullptr, nullptr, mid, nullptr, kDim, kMlp);
    gemm_kernel<2, 128><<<dim3(kDim / 128, kRows / 128), 256, 0, stream>>>(
        mid, w2T, b2 + L * kDim, s2 + L * kDim, xo, nullptr, nullptr, kMlp, kDim);
  }
}

// Round 15
// 3387.461 us; speedup vs baseline: 1.3377x; 1.0099x over previous
//
#include <hip/hip_runtime.h>

constexpr int kDepth = 6;
constexpr int kB = 8;
constexpr int kN = 1024;
constexpr int kDim = 768;
constexpr int kH = 12;
constexpr int kDh = 64;
constexpr int kMlp = 3072;
constexpr int kRows = kB * kN;   // 8192
constexpr int kQKV = 2304;       // q(768) k(768) v(768)

typedef __attribute__((ext_vector_type(4))) float f32x4;
typedef __attribute__((ext_vector_type(8))) short bf16x8;

__device__ __forceinline__ f32x4 mfma16x16x32(bf16x8 a, bf16x8 b, f32x4 c) {
  return __builtin_amdgcn_mfma_f32_16x16x32_bf16(a, b, c, 0, 0, 0);
}

__device__ __forceinline__ unsigned short f2bf(float f) {
  unsigned int u = __builtin_bit_cast(unsigned int, f);
  u = u + 0x7FFFu + ((u >> 16) & 1u);
  return (unsigned short)(u >> 16);
}

__device__ __forceinline__ float bf2f(unsigned short u) {
  return __builtin_bit_cast(float, (unsigned int)u << 16);
}

__device__ __forceinline__ void gload_lds16(const void* g, void* l) {
  __builtin_amdgcn_global_load_lds((__attribute__((address_space(1))) void*)g,
                                   (__attribute__((address_space(3))) void*)l,
                                   16, 0, 0);
}

// ---------------- LayerNorm: f32 in -> bf16 out ----------------
__global__ __launch_bounds__(256) void ln_kernel(const float* __restrict__ x,
                                                 const float* __restrict__ gamma,
                                                 const float* __restrict__ beta,
                                                 unsigned short* __restrict__ out) {
  int row = blockIdx.x, tid = threadIdx.x;
  const float* xr = x + (size_t)row * kDim;
  float v0 = xr[tid], v1 = xr[tid + 256], v2 = xr[tid + 512];
  float s = v0 + v1 + v2;
  float q = v0 * v0 + v1 * v1 + v2 * v2;
#pragma unroll
  for (int o = 32; o >= 1; o >>= 1) {
    s += __shfl_xor(s, o);
    q += __shfl_xor(q, o);
  }
  __shared__ float ss[4], sq[4];
  int wid = tid >> 6, lane = tid & 63;
  if (lane == 0) { ss[wid] = s; sq[wid] = q; }
  __syncthreads();
  s = ss[0] + ss[1] + ss[2] + ss[3];
  q = sq[0] + sq[1] + sq[2] + sq[3];
  float mean = s * (1.0f / kDim);
  float var = q * (1.0f / kDim) - mean * mean;
  float rstd = rsqrtf(var + 1e-5f);
  unsigned short* orow = out + (size_t)row * kDim;
  orow[tid]       = f2bf((v0 - mean) * rstd * gamma[tid]       + beta[tid]);
  orow[tid + 256] = f2bf((v1 - mean) * rstd * gamma[tid + 256] + beta[tid + 256]);
  orow[tid + 512] = f2bf((v2 - mean) * rstd * gamma[tid + 512] + beta[tid + 512]);
}

// ---------------- Batched weight transpose: all 5 matrices of one layer ----------------
__global__ __launch_bounds__(256) void transpose_all(const float* __restrict__ Wq,
                                                     const float* __restrict__ Wkv,
                                                     const float* __restrict__ Wo,
                                                     const float* __restrict__ W1,
                                                     const float* __restrict__ W2,
                                                     unsigned short* __restrict__ wqkvT,
                                                     unsigned short* __restrict__ woT,
                                                     unsigned short* __restrict__ w1T,
                                                     unsigned short* __restrict__ w2T,
                                                     int L) {
  int t = blockIdx.x;
  const float* src;
  unsigned short* dst;
  int R, C, dstOff;
  if (t < 576)       { src = Wq  + (size_t)L * 768 * 768;  R = 768;  C = 768;  dst = wqkvT; dstOff = 0;   }
  else if (t < 1728) { src = Wkv + (size_t)L * 768 * 1536; R = 768;  C = 1536; dst = wqkvT; dstOff = 768; t -= 576; }
  else if (t < 2304) { src = Wo  + (size_t)L * 768 * 768;  R = 768;  C = 768;  dst = woT;   dstOff = 0;   t -= 1728; }
  else if (t < 4608) { src = W1  + (size_t)L * 768 * 3072; R = 768;  C = 3072; dst = w1T;   dstOff = 0;   t -= 2304; }
  else               { src = W2  + (size_t)L * 3072 * 768; R = 3072; C = 768;  dst = w2T;   dstOff = 0;   t -= 4608; }
  int Ct = C >> 5;
  int bx = t % Ct, by = t / Ct;
  __shared__ float tt[32][33];
  int tx = threadIdx.x & 31, ty = threadIdx.x >> 5;  // ty 0..7
  int c0 = bx * 32, r0 = by * 32;
#pragma unroll
  for (int k = 0; k < 4; ++k) {
    int r = r0 + ty + k * 8;
    tt[ty + k * 8][tx] = src[(size_t)r * C + c0 + tx];
  }
  __syncthreads();
#pragma unroll
  for (int k = 0; k < 4; ++k) {
    int c = c0 + ty + k * 8;
    dst[(size_t)(dstOff + c) * R + r0 + tx] = f2bf(tt[tx][ty + k * 8]);
  }
}

// ---------------- GEMM: A[M,K]bf16 x Bt[N,K]bf16 -> epilogue ----------------
// EPI 0: C=bf16 plain; EPI 1: bf16 gelu(acc+bias); EPI 2: resid += (acc+bias)*scl
// EPI 3: QKV fused: cols<1536 -> qkv bf16; cols>=1536 -> vT[(b*12+g)*64+d][j] packed stores
template <int EPI, int BK>
__global__ __launch_bounds__(256) void gemm_kernel(const unsigned short* __restrict__ A,
                                                   const unsigned short* __restrict__ Bt,
                                                   const float* __restrict__ bias,
                                                   const float* __restrict__ scl,
                                                   float* __restrict__ resid,
                                                   unsigned short* __restrict__ C,
                                                   unsigned short* __restrict__ vT,
                                                   int K, int ldc) {
  __shared__ __align__(16) unsigned short lA[128 * BK];
  __shared__ __align__(16) unsigned short lB[128 * BK];
  int tid = threadIdx.x, wid = tid >> 6, lane = tid & 63;
  // XCD-aware bijective chunked swizzle (all grids have nwg % 8 == 0)
  int gx = gridDim.x;
  int nwg = gx * gridDim.y;
  int orig = blockIdx.y * gx + blockIdx.x;
  int chunk = nwg >> 3;
  int wg = (orig & 7) * chunk + (orig >> 3);
  int bx = wg % gx, by = wg / gx;
  int row0 = by * 128, col0 = bx * 128;
  int wr = wid >> 1, wc = wid & 1;
  f32x4 zero = {0.f, 0.f, 0.f, 0.f};
  f32x4 acc[4][4];
#pragma unroll
  for (int m = 0; m < 4; ++m)
#pragma unroll
    for (int n = 0; n < 4; ++n) acc[m][n] = zero;

  constexpr int SL = BK / 8;                 // 16B slots per row
  constexpr int PT = (128 * SL) / 256;       // chunks per thread per matrix

  for (int kt = 0; kt < K; kt += BK) {
    __syncthreads();
#pragma unroll
    for (int t = 0; t < PT; ++t) {
      int c = t * 256 + tid;
      int r = c / SL, slot = c % SL;
      int k8 = (slot & ~7) | ((slot & 7) ^ (r & 7));  // source-swizzle (low 3 bits)
      gload_lds16(&A[(size_t)(row0 + r) * K + kt + k8 * 8], &lA[c * 8]);
      gload_lds16(&Bt[(size_t)(col0 + r) * K + kt + k8 * 8], &lB[c * 8]);
    }
    __syncthreads();
#pragma unroll
    for (int kk = 0; kk < BK / 32; ++kk) {
      bf16x8 af[4], bfr[4];
      int kslot = kk * 4 + (lane >> 4);
#pragma unroll
      for (int m = 0; m < 4; ++m) {
        int r = wr * 64 + m * 16 + (lane & 15);
        int koff = ((kslot & ~7) | ((kslot & 7) ^ (r & 7))) << 3;
        af[m] = *reinterpret_cast<const bf16x8*>(&lA[r * BK + koff]);
      }
#pragma unroll
      for (int n = 0; n < 4; ++n) {
        int r = wc * 64 + n * 16 + (lane & 15);
        int koff = ((kslot & ~7) | ((kslot & 7) ^ (r & 7))) << 3;
        bfr[n] = *reinterpret_cast<const bf16x8*>(&lB[r * BK + koff]);
      }
#pragma unroll
      for (int m = 0; m < 4; ++m)
#pragma unroll
        for (int n = 0; n < 4; ++n) acc[m][n] = mfma16x16x32(af[m], bfr[n], acc[m][n]);
    }
  }

  if (EPI == 3 && col0 >= 1536) {
    // V-region tile: write straight to vT (transpose fused); 4 consecutive j per lane -> u64
#pragma unroll
    for (int m = 0; m < 4; ++m)
#pragma unroll
      for (int n = 0; n < 4; ++n) {
        int row = row0 + wr * 64 + m * 16 + ((lane >> 4) << 2);
        int col = col0 + wc * 64 + n * 16 + (lane & 15);
        int d = col - 1536;
        int b = row >> 10, j = row & 1023;
        int g = d >> 6, dd = d & 63;
        unsigned short tmp[4];
#pragma unroll
        for (int r4 = 0; r4 < 4; ++r4) tmp[r4] = f2bf(acc[m][n][r4]);
        *(unsigned long long*)&vT[((size_t)((b * 12 + g) * 64 + dd)) * kN + j] =
            *(unsigned long long*)tmp;
      }
    return;
  }
#pragma unroll
  for (int m = 0; m < 4; ++m)
#pragma unroll
    for (int n = 0; n < 4; ++n)
#pragma unroll
      for (int r4 = 0; r4 < 4; ++r4) {
        int row = row0 + wr * 64 + m * 16 + ((lane >> 4) << 2) + r4;
        int col = col0 + wc * 64 + n * 16 + (lane & 15);
        float v = acc[m][n][r4];
        if (EPI == 0 || EPI == 3) {
          C[(size_t)row * ldc + col] = f2bf(v);
        } else if (EPI == 1) {
          v += bias[col];
          v = 0.5f * v * (1.f + erff(v * 0.70710678118654752f));
          C[(size_t)row * ldc + col] = f2bf(v);
        } else {
          v = (v + bias[col]) * scl[col];
          size_t idx = (size_t)row * kDim + col;
          resid[idx] = resid[idx] + v;
        }
      }
}

// ---------------- QK^T raw per-head scores -> dots bf16, layout [b][i][j][h12] ----------------
// 24B per (i,j) slot, written/read as 8B-aligned u64 triples.
__global__ __launch_bounds__(256) void dots_kernel(const unsigned short* __restrict__ qkv,
                                                   unsigned short* __restrict__ dots,
                                                   int i0, int IC) {
  constexpr int TROW = 24;  // ushorts per (i,j) slot in LDS staging (12 h + pad)
  __shared__ __align__(16) unsigned short T[32 * 32 * TROW];  // 48KB
  int tid = threadIdx.x, wid = tid >> 6, lane = tid & 63;
  int kg = lane >> 4, l15 = lane & 15;
  int j0 = blockIdx.x * 32;
  int il0 = blockIdx.y * 32;
  int b = blockIdx.z;
  f32x4 zero = {0.f, 0.f, 0.f, 0.f};
#pragma unroll
  for (int rep = 0; rep < 3; ++rep) {
    int h = rep * 4 + wid;
    f32x4 acc[2][2];
    acc[0][0] = zero; acc[0][1] = zero; acc[1][0] = zero; acc[1][1] = zero;
#pragma unroll
    for (int kk = 0; kk < 2; ++kk) {
      bf16x8 aq[2], bk[2];
#pragma unroll
      for (int m = 0; m < 2; ++m) {
        int tok = i0 + il0 + m * 16 + l15;
        aq[m] = *reinterpret_cast<const bf16x8*>(
            &qkv[(size_t)(b * kN + tok) * kQKV + h * 64 + kk * 32 + kg * 8]);
      }
#pragma unroll
      for (int n = 0; n < 2; ++n) {
        int tj = j0 + n * 16 + l15;
        bk[n] = *reinterpret_cast<const bf16x8*>(
            &qkv[(size_t)(b * kN + tj) * kQKV + 768 + h * 64 + kk * 32 + kg * 8]);
      }
#pragma unroll
      for (int m = 0; m < 2; ++m)
#pragma unroll
        for (int n = 0; n < 2; ++n) acc[m][n] = mfma16x16x32(aq[m], bk[n], acc[m][n]);
    }
#pragma unroll
    for (int m = 0; m < 2; ++m)
#pragma unroll
      for (int n = 0; n < 2; ++n)
#pragma unroll
        for (int r = 0; r < 4; ++r)
          T[((m * 16 + kg * 4 + r) * 32 + n * 16 + l15) * TROW + h] = f2bf(acc[m][n][r]);
  }
  __syncthreads();
  // packed 24B write-out: 1024 slots, 4 per thread, 3x u64 each (8B-aligned)
#pragma unroll
  for (int k = 0; k < 4; ++k) {
    int s = tid + k * 256;
    int ii = s >> 5, jj = s & 31;
    size_t o = ((size_t)(b * IC + il0 + ii) * kN + j0 + jj) * 12;
    const unsigned short* src = &T[s * TROW];
    *(unsigned long long*)&dots[o]     = *(const unsigned long long*)&src[0];
    *(unsigned long long*)&dots[o + 4] = *(const unsigned long long*)&src[4];
    *(unsigned long long*)&dots[o + 8] = *(const unsigned long long*)&src[8];
  }
}

// ---------------- MFMA premix + softmax (no-max+clamp) + MFMA postmix -> p bf16 ----------------
// dots layout [b][i][j][h12] (24B slots); kg=1 fragment upper half reads next slot's h0..3 —
// finite garbage, zero-weighted by preA's k>=12 zero columns. pbuf layout [b][g2][i][j].
__global__ __launch_bounds__(256) void softmax_mix_kernel(const unsigned short* __restrict__ dots,
                                                          const float* __restrict__ pre,
                                                          const float* __restrict__ post,
                                                          unsigned short* __restrict__ pbuf,
                                                          int IC) {
  constexpr int EROW = 24;  // ushorts per j row of E (16 g + 8 pad, 16B-aligned)
  __shared__ __align__(16) unsigned short E[1024 * EROW];   // 48KB
  __shared__ __align__(16) unsigned short preA[16 * 32];
  __shared__ __align__(16) unsigned short postA[16 * 32];
  __shared__ float red[4][16];
  __shared__ float lgs[16];
  int tid = threadIdx.x, wid = tid >> 6, lane = tid & 63;
  int kg = lane >> 4, l15 = lane & 15;
  int i = blockIdx.x, b = blockIdx.y;
  // build preA[m=g][k=h] = pre[h][g] * 0.125, zero-padded (k>=12 zero kills garbage)
  for (int idx = tid; idx < 512; idx += 256) {
    int m = idx >> 5, k = idx & 31;
    preA[idx] = f2bf((m < 12 && k < 12) ? pre[k * 12 + m] * 0.125f : 0.f);
  }
  __syncthreads();
  bf16x8 preF = *(const bf16x8*)&preA[l15 * 32 + kg * 8];
  const unsigned short* drow = dots + (size_t)(b * IC + i) * kN * 12;
  f32x4 zero = {0.f, 0.f, 0.f, 0.f};
  bf16x8 zfrag = {0, 0, 0, 0, 0, 0, 0, 0};
  float psum[4] = {0.f, 0.f, 0.f, 0.f};
  // pass A: premix via MFMA, exp, stash E[j][g], accumulate psum
#pragma unroll
  for (int grp = 0; grp < 16; ++grp) {
    int j = wid * 256 + grp * 16 + l15;
    bf16x8 bfrag = zfrag;
    if (kg < 2) {
      union { unsigned long long q[2]; bf16x8 v; } u;
      size_t base = (size_t)j * 12 + kg * 8;
      u.q[0] = *(const unsigned long long*)&drow[base];
      u.q[1] = *(const unsigned long long*)&drow[base + 4];
      bfrag = u.v;
    }
    f32x4 d = mfma16x16x32(preF, bfrag, zero);  // D[g=kg*4+r][j=l15]
    float ee[4];
#pragma unroll
    for (int r = 0; r < 4; ++r) {
      float dc = fminf(fmaxf(d[r], -15.f), 15.f);
      ee[r] = (kg == 3) ? 0.f : __expf(dc);
      psum[r] += ee[r];
    }
    unsigned int w0, w1;
    asm("v_cvt_pk_bf16_f32 %0, %1, %2" : "=v"(w0) : "v"(ee[0]), "v"(ee[1]));
    asm("v_cvt_pk_bf16_f32 %0, %1, %2" : "=v"(w1) : "v"(ee[2]), "v"(ee[3]));
    *(unsigned int*)&E[j * EROW + kg * 4] = w0;
    *(unsigned int*)&E[j * EROW + kg * 4 + 2] = w1;
  }
  // reduce psum over 16 cols (l15 lanes), then 4 waves
#pragma unroll
  for (int r = 0; r < 4; ++r) {
    psum[r] += __shfl_xor(psum[r], 1);
    psum[r] += __shfl_xor(psum[r], 2);
    psum[r] += __shfl_xor(psum[r], 4);
    psum[r] += __shfl_xor(psum[r], 8);
  }
  if (l15 == 0) {
#pragma unroll
    for (int r = 0; r < 4; ++r) red[wid][kg * 4 + r] = psum[r];
  }
  __syncthreads();
  if (tid < 16) {
    float s = red[0][tid] + red[1][tid] + red[2][tid] + red[3][tid];
    lgs[tid] = (tid < 12) ? 1.f / s : 0.f;
  }
  __syncthreads();
  // build postA[m=g2][k=g] = post[g][g2] * lg[g], zero-padded
  for (int idx = tid; idx < 512; idx += 256) {
    int m = idx >> 5, k = idx & 31;
    postA[idx] = f2bf((m < 12 && k < 12) ? post[k * 12 + m] * lgs[k] : 0.f);
  }
  __syncthreads();
  bf16x8 postF = *(const bf16x8*)&postA[l15 * 32 + kg * 8];
  // pass B: postmix via MFMA, write p
#pragma unroll
  for (int grp = 0; grp < 16; ++grp) {
    int j = wid * 256 + grp * 16 + l15;
    bf16x8 efrag = (kg < 2) ? *(const bf16x8*)&E[j * EROW + kg * 8] : zfrag;
    f32x4 d2 = mfma16x16x32(postF, efrag, zero);  // D[g2=kg*4+r][j=l15]
    if (kg < 3) {
#pragma unroll
      for (int r = 0; r < 4; ++r) {
        int g2 = kg * 4 + r;
        pbuf[((size_t)(b * kH + g2) * IC + i) * kN + j] = f2bf(d2[r]);
      }
    }
  }
}

// ---------------- PV: out[b,i,g*64+d] = sum_j p[b,g,i,j] * v[b,g,j,d] (32 i-rows/block) --------
__global__ __launch_bounds__(256) void pv_kernel(const unsigned short* __restrict__ pbuf,
                                                 const unsigned short* __restrict__ vT,
                                                 unsigned short* __restrict__ attn_out,
                                                 int i0, int IC) {
  int tid = threadIdx.x, wid = tid >> 6, lane = tid & 63;
  int kg = lane >> 4, l15 = lane & 15;
  int i32 = blockIdx.x * 32;
  int g = blockIdx.y, b = blockIdx.z;
  const unsigned short* prow = pbuf + (size_t)(b * kH + g) * IC * kN;
  const unsigned short* vrow = vT + (size_t)(b * kH + g) * kDh * kN;
  f32x4 zero = {0.f, 0.f, 0.f, 0.f};
  f32x4 acc[2][4];
#pragma unroll
  for (int half = 0; half < 2; ++half)
#pragma unroll
    for (int n = 0; n < 4; ++n) acc[half][n] = zero;
#pragma unroll
  for (int s = 0; s < 8; ++s) {
    int kt = (wid * 8 + s) * 32 + kg * 8;
    bf16x8 ap[2];
#pragma unroll
    for (int half = 0; half < 2; ++half)
      ap[half] = *reinterpret_cast<const bf16x8*>(&prow[(size_t)(i32 + half * 16 + l15) * kN + kt]);
#pragma unroll
    for (int n = 0; n < 4; ++n) {
      bf16x8 bv = *reinterpret_cast<const bf16x8*>(&vrow[(size_t)(n * 16 + l15) * kN + kt]);
#pragma unroll
      for (int half = 0; half < 2; ++half)
        acc[half][n] = mfma16x16x32(ap[half], bv, acc[half][n]);
    }
  }
  __shared__ float red[3][32][64];
  if (wid > 0) {
#pragma unroll
    for (int half = 0; half < 2; ++half)
#pragma unroll
      for (int n = 0; n < 4; ++n)
#pragma unroll
        for (int r = 0; r < 4; ++r)
          red[wid - 1][half * 16 + kg * 4 + r][n * 16 + l15] = acc[half][n][r];
  }
  __syncthreads();
  if (wid == 0) {
#pragma unroll
    for (int half = 0; half < 2; ++half)
#pragma unroll
      for (int n = 0; n < 4; ++n)
#pragma unroll
        for (int r = 0; r < 4; ++r) {
          int rr = half * 16 + kg * 4 + r, cc = n * 16 + l15;
          float v = acc[half][n][r] + red[0][rr][cc] + red[1][rr][cc] + red[2][rr][cc];
          int tok = i0 + i32 + rr;
          attn_out[(size_t)(b * kN + tok) * kDim + g * kDh + cc] = f2bf(v);
        }
  }
}

extern "C" void kernel_launch(void* const* d_in, const int* in_sizes, int n_in,
                              void* d_out, int out_size, void* d_ws, size_t ws_size,
                              hipStream_t stream) {
  (void)in_sizes; (void)n_in; (void)out_size;
  const float* x     = (const float*)d_in[0];
  const float* ln1_g = (const float*)d_in[1];
  const float* ln1_b = (const float*)d_in[2];
  const float* Wq    = (const float*)d_in[3];
  const float* Wkv   = (const float*)d_in[4];
  const float* pre   = (const float*)d_in[5];
  const float* post  = (const float*)d_in[6];
  const float* Wo    = (const float*)d_in[7];
  const float* bo    = (const float*)d_in[8];
  const float* s1    = (const float*)d_in[9];
  const float* ln2_g = (const float*)d_in[10];
  const float* ln2_b = (const float*)d_in[11];
  const float* W1    = (const float*)d_in[12];
  const float* b1    = (const float*)d_in[13];
  const float* W2    = (const float*)d_in[14];
  const float* b2    = (const float*)d_in[15];
  const float* s2    = (const float*)d_in[16];
  float* xo = (float*)d_out;

  char* ws = (char*)d_ws;
  size_t off = 0;
  auto alloc = [&](size_t bytes) -> void* {
    void* p = ws + off;
    off += (bytes + 255) & ~(size_t)255;
    return p;
  };
  unsigned short* h_buf   = (unsigned short*)alloc((size_t)kRows * kDim * 2);
  unsigned short* qkv     = (unsigned short*)alloc((size_t)kRows * kQKV * 2);
  unsigned short* vT      = (unsigned short*)alloc((size_t)kB * kH * kDh * kN * 2);
  unsigned short* attnout = (unsigned short*)alloc((size_t)kRows * kDim * 2);
  unsigned short* mid     = (unsigned short*)alloc((size_t)kRows * kMlp * 2);
  unsigned short* wqkvT   = (unsigned short*)alloc((size_t)kQKV * kDim * 2);
  unsigned short* woT     = (unsigned short*)alloc((size_t)kDim * kDim * 2);
  unsigned short* w1T     = (unsigned short*)alloc((size_t)kMlp * kDim * 2);
  unsigned short* w2T     = (unsigned short*)alloc((size_t)kDim * kMlp * 2);

  size_t base = off;
  // per-i-row bytes: dots [b][i][j][h12] bf16 = 8*1024*12*2 = 196608; pbuf = 196608
  int IC = 1024;
  while (IC > 32 && base + (size_t)IC * (196608 + 196608) + 1024 > ws_size) IC >>= 1;
  unsigned short* dots = (unsigned short*)alloc((size_t)kB * IC * kN * 12 * 2);
  unsigned short* pbuf = (unsigned short*)alloc((size_t)kB * kH * IC * kN * 2);

  hipMemcpyAsync(xo, x, (size_t)kRows * kDim * 4, hipMemcpyDeviceToDevice, stream);

  for (int L = 0; L < kDepth; ++L) {
    // --- attention block ---
    ln_kernel<<<kRows, 256, 0, stream>>>(xo, ln1_g + L * kDim, ln1_b + L * kDim, h_buf);
    transpose_all<<<6912, 256, 0, stream>>>(Wq, Wkv, Wo, W1, W2, wqkvT, woT, w1T, w2T, L);

    // QKV GEMM with fused V-transpose epilogue (V cols go straight to vT)
    gemm_kernel<3, 64><<<dim3(kQKV / 128, kRows / 128), 256, 0, stream>>>(
        h_buf, wqkvT, nullptr, nullptr, nullptr, qkv, vT, kDim, kQKV);

    for (int i0 = 0; i0 < kN; i0 += IC) {
      dots_kernel<<<dim3(kN / 32, IC / 32, kB), 256, 0, stream>>>(qkv, dots, i0, IC);
      softmax_mix_kernel<<<dim3(IC, kB), 256, 0, stream>>>(
          dots, pre + L * 144, post + L * 144, pbuf, IC);
      pv_kernel<<<dim3(IC / 32, kH, kB), 256, 0, stream>>>(pbuf, vT, attnout, i0, IC);
    }
    gemm_kernel<2, 128><<<dim3(kDim / 128, kRows / 128), 256, 0, stream>>>(
        attnout, woT, bo + L * kDim, s1 + L * kDim, xo, nullptr, nullptr, kDim, kDim);

    // --- MLP block ---
    ln_kernel<<<kRows, 256, 0, stream>>>(xo, ln2_g + L * kDim, ln2_b + L * kDim, h_buf);
    gemm_kernel<1, 64><<<dim3(kMlp / 128, kRows / 128), 256, 0, stream>>>(
        h_buf, w1T, b1 + L * kMlp, nullptr, nullptr, mid, nullptr, kDim, kMlp);
    gemm_kernel<2, 128><<<dim3(kDim / 128, kRows / 128), 256, 0, stream>>>(
        mid, w2T, b2 + L * kDim, s2 + L * kDim, xo, nullptr, nullptr, kMlp, kDim);
  }
}